// Round 1
// baseline (1330.202 us; speedup 1.0000x reference)
//
#include <hip/hip_runtime.h>
#include <hip/hip_bf16.h>

#define IN_F 512
#define HID_F 256
#define OUT_F 16

typedef __bf16 bf8_t __attribute__((ext_vector_type(8)));
typedef float f4_t __attribute__((ext_vector_type(4)));
typedef unsigned short u16x4 __attribute__((ext_vector_type(4)));

__device__ __forceinline__ unsigned short f2b(float f) {
  union { float f; unsigned u; } a; a.f = f;
  unsigned u = a.u;
  u += 0x7fffu + ((u >> 16) & 1u);   // round-to-nearest-even bf16
  return (unsigned short)(u >> 16);
}

// Detect whether edge_index arrived as int64 (odd 32-bit words all zero) or int32.
__global__ void detect_k(const int* __restrict__ ei, int* __restrict__ flag) {
  if (threadIdx.x == 0 && blockIdx.x == 0) {
    int is64 = 1;
    for (int i = 0; i < 16; ++i)
      if (ei[2 * i + 1] != 0) is64 = 0;
    *flag = is64;
  }
}

// Fused MLP: h = relu(x@W1^T + b1) @ W2^T + b2, bf16 MFMA, 64 nodes/block.
__global__ __launch_bounds__(256) void mlp_k(
    const float* __restrict__ x, const float* __restrict__ W1,
    const float* __restrict__ b1, const float* __restrict__ W2,
    const float* __restrict__ b2, float* __restrict__ h, int n) {
  __shared__ unsigned short a_sh[64][40];     // 64 nodes x 32 k (pad 8)
  __shared__ unsigned short w_sh[256][40];    // 256 hid x 32 k
  __shared__ unsigned short hid_sh[64][264];  // 64 nodes x 256 hid (pad 8)
  __shared__ unsigned short w2_sh[16][264];   // 16 out x 256 hid
  int tid = threadIdx.x;
  int node0 = blockIdx.x * 64;
  int wvid = tid >> 6;
  int lane = tid & 63;
  int row16 = lane & 15;
  int kg = lane >> 4;

  // stage W2 (16x256) -> bf16 LDS
  {
    int r = tid >> 4;
    int c0 = (tid & 15) * 16;
    const float* src = W2 + r * HID_F + c0;
    #pragma unroll
    for (int j = 0; j < 16; j += 4) {
      float4 v = *(const float4*)(src + j);
      u16x4 s = { f2b(v.x), f2b(v.y), f2b(v.z), f2b(v.w) };
      *(u16x4*)&w2_sh[r][c0 + j] = s;
    }
  }

  f4_t acc[4][4];
  #pragma unroll
  for (int mi = 0; mi < 4; ++mi)
    #pragma unroll
    for (int ni = 0; ni < 4; ++ni)
      acc[mi][ni] = (f4_t){0.f, 0.f, 0.f, 0.f};

  for (int kc = 0; kc < 16; ++kc) {
    int kb = kc * 32;
    __syncthreads();
    // stage A: x[node0..node0+63][kb..kb+31]
    {
      int r = tid >> 3;
      int c = (tid & 7) * 4;
      #pragma unroll
      for (int p = 0; p < 2; ++p) {
        int rr = p * 32 + r;
        int node = node0 + rr;
        float4 v;
        if (node < n) v = *(const float4*)(x + (size_t)node * IN_F + kb + c);
        else { v.x = 0.f; v.y = 0.f; v.z = 0.f; v.w = 0.f; }
        u16x4 s = { f2b(v.x), f2b(v.y), f2b(v.z), f2b(v.w) };
        *(u16x4*)&a_sh[rr][c] = s;
      }
    }
    // stage W1: W1[0..255][kb..kb+31]
    {
      int r = tid >> 3;
      int c = (tid & 7) * 4;
      #pragma unroll
      for (int p = 0; p < 8; ++p) {
        int rr = p * 32 + r;
        float4 v = *(const float4*)(W1 + (size_t)rr * IN_F + kb + c);
        u16x4 s = { f2b(v.x), f2b(v.y), f2b(v.z), f2b(v.w) };
        *(u16x4*)&w_sh[rr][c] = s;
      }
    }
    __syncthreads();
    bf8_t af[4], bfr[4];
    #pragma unroll
    for (int mi = 0; mi < 4; ++mi)
      af[mi] = *(const bf8_t*)&a_sh[mi * 16 + row16][kg * 8];
    #pragma unroll
    for (int ni = 0; ni < 4; ++ni)
      bfr[ni] = *(const bf8_t*)&w_sh[wvid * 64 + ni * 16 + row16][kg * 8];
    #pragma unroll
    for (int mi = 0; mi < 4; ++mi)
      #pragma unroll
      for (int ni = 0; ni < 4; ++ni)
        acc[mi][ni] = __builtin_amdgcn_mfma_f32_16x16x32_bf16(af[mi], bfr[ni], acc[mi][ni], 0, 0, 0);
  }
  __syncthreads();
  // epilogue 1: +b1, relu, -> hid_sh bf16.  C/D layout: col=lane&15, row=kg*4+r
  #pragma unroll
  for (int mi = 0; mi < 4; ++mi) {
    #pragma unroll
    for (int ni = 0; ni < 4; ++ni) {
      int col = wvid * 64 + ni * 16 + row16;
      float bias = b1[col];
      #pragma unroll
      for (int r = 0; r < 4; ++r) {
        int nl = mi * 16 + kg * 4 + r;
        float v = acc[mi][ni][r] + bias;
        v = fmaxf(v, 0.f);
        hid_sh[nl][col] = f2b(v);
      }
    }
  }
  __syncthreads();
  // GEMM2: each wave does 16 nodes x 16 out, K=256
  f4_t acc2 = (f4_t){0.f, 0.f, 0.f, 0.f};
  #pragma unroll
  for (int kc = 0; kc < 8; ++kc) {
    bf8_t a2  = *(const bf8_t*)&hid_sh[wvid * 16 + row16][kc * 32 + kg * 8];
    bf8_t b2f = *(const bf8_t*)&w2_sh[row16][kc * 32 + kg * 8];
    acc2 = __builtin_amdgcn_mfma_f32_16x16x32_bf16(a2, b2f, acc2, 0, 0, 0);
  }
  float bias2 = b2[row16];
  #pragma unroll
  for (int r = 0; r < 4; ++r) {
    int nl = wvid * 16 + kg * 4 + r;
    int node = node0 + nl;
    if (node < n) h[(size_t)node * OUT_F + row16] = acc2[r] + bias2;
  }
}

// in-degree histogram over col
__global__ void hist_k(const int* __restrict__ ei, int* __restrict__ cnt,
                       const int* __restrict__ flag, int E_) {
  int e = blockIdx.x * 256 + threadIdx.x;
  if (e >= E_) return;
  int is64 = *flag;
  int c = is64 ? ei[2 * (E_ + e)] : ei[E_ + e];
  atomicAdd(&cnt[c], 1);
}

__global__ void dinv_k(const int* __restrict__ cnt, float* __restrict__ dinv, int n) {
  int i = blockIdx.x * 256 + threadIdx.x;
  if (i < n) dinv[i] = rsqrtf((float)(cnt[i] + 1));
}

// block-level exclusive scan (1024 elems/block, 4/thread)
__global__ void scan_blocks(const int* __restrict__ cnt, int* __restrict__ offs,
                            int* __restrict__ bsum, int n) {
  __shared__ int wsum[4];
  int tid = threadIdx.x;
  int base = blockIdx.x * 1024 + tid * 4;
  int v0 = (base + 0 < n) ? cnt[base + 0] : 0;
  int v1 = (base + 1 < n) ? cnt[base + 1] : 0;
  int v2 = (base + 2 < n) ? cnt[base + 2] : 0;
  int v3 = (base + 3 < n) ? cnt[base + 3] : 0;
  int tsum = v0 + v1 + v2 + v3;
  int lane = tid & 63, wv = tid >> 6;
  int inc = tsum;
  #pragma unroll
  for (int off = 1; off < 64; off <<= 1) {
    int t = __shfl_up(inc, off, 64);
    if (lane >= off) inc += t;
  }
  if (lane == 63) wsum[wv] = inc;
  __syncthreads();
  int add = 0;
  #pragma unroll
  for (int j = 0; j < 4; ++j)
    if (j < wv) add += wsum[j];
  int ex = add + inc - tsum;
  if (base + 0 < n) offs[base + 0] = ex;
  if (base + 1 < n) offs[base + 1] = ex + v0;
  if (base + 2 < n) offs[base + 2] = ex + v0 + v1;
  if (base + 3 < n) offs[base + 3] = ex + v0 + v1 + v2;
  if (tid == 255) bsum[blockIdx.x] = add + inc;
}

// exclusive scan of block sums (nb <= 128), one block of 128 threads
__global__ void scan_top(int* __restrict__ bsum, int nb) {
  __shared__ int w0;
  int tid = threadIdx.x;
  int v = (tid < nb) ? bsum[tid] : 0;
  int inc = v;
  #pragma unroll
  for (int off = 1; off < 64; off <<= 1) {
    int t = __shfl_up(inc, off, 64);
    if ((tid & 63) >= off) inc += t;
  }
  if (tid == 63) w0 = inc;
  __syncthreads();
  int ex = inc - v + ((tid >= 64) ? w0 : 0);
  if (tid < nb) bsum[tid] = ex;
}

__global__ void scan_add(int* __restrict__ offs, const int* __restrict__ bsum,
                         int* __restrict__ cursor, int n) {
  int base = blockIdx.x * 1024 + threadIdx.x * 4;
  int b = bsum[blockIdx.x];
  #pragma unroll
  for (int j = 0; j < 4; ++j) {
    int i = base + j;
    if (i < n) { int v = offs[i] + b; offs[i] = v; cursor[i] = v; }
  }
}

// scatter edges into CSR (by destination), weight = dinv[src]*dinv[dst]
__global__ void scatter_k(const int* __restrict__ ei, const float* __restrict__ dinv,
                          int* __restrict__ cursor, int* __restrict__ nbr,
                          float* __restrict__ wv, const int* __restrict__ flag, int E_) {
  int e = blockIdx.x * 256 + threadIdx.x;
  if (e >= E_) return;
  int is64 = *flag;
  int r, c;
  if (is64) { r = ei[2 * e]; c = ei[2 * (E_ + e)]; }
  else      { r = ei[e];     c = ei[E_ + e]; }
  int pos = atomicAdd(&cursor[c], 1);
  nbr[pos] = r;
  wv[pos] = dinv[r] * dinv[c];
}

// one APPNP iteration: zout = 0.9*(A_hat zin) + 0.1*h ; 16 lanes per node
__global__ __launch_bounds__(256) void prop_k(
    const float* __restrict__ zin, float* __restrict__ zout,
    const float* __restrict__ h, const int* __restrict__ offs,
    const int* __restrict__ cnt, const int* __restrict__ nbr,
    const float* __restrict__ wv, const float* __restrict__ dinv, int n) {
  int tid = threadIdx.x;
  int node = blockIdx.x * 16 + (tid >> 4);
  int lane = tid & 15;
  if (node >= n) return;
  float di = dinv[node];
  int base = node * OUT_F + lane;
  float acc = di * di * zin[base];     // self loop
  int s = offs[node];
  int end = s + cnt[node];
  int e = s;
  for (; e + 2 <= end; e += 2) {
    int j0 = nbr[e], j1 = nbr[e + 1];
    float w0 = wv[e], w1 = wv[e + 1];
    acc += w0 * zin[j0 * OUT_F + lane];
    acc += w1 * zin[j1 * OUT_F + lane];
  }
  if (e < end) acc += wv[e] * zin[nbr[e] * OUT_F + lane];
  zout[base] = 0.9f * acc + 0.1f * h[base];
}

__global__ void lsm_k(const float* __restrict__ z, float* __restrict__ out, int n) {
  int gid = blockIdx.x * 256 + threadIdx.x;
  if (gid >= n * OUT_F) return;
  float v = z[gid];
  float m = v;
  #pragma unroll
  for (int s = 8; s; s >>= 1) m = fmaxf(m, __shfl_xor(m, s));
  float e = expf(v - m);
  float t = e;
  #pragma unroll
  for (int s = 8; s; s >>= 1) t += __shfl_xor(t, s);
  out[gid] = v - m - logf(t);
}

extern "C" void kernel_launch(void* const* d_in, const int* in_sizes, int n_in,
                              void* d_out, int out_size, void* d_ws, size_t ws_size,
                              hipStream_t stream) {
  const int Nn = in_sizes[0] / IN_F;
  const int Ee = in_sizes[1] / 2;
  const float* x  = (const float*)d_in[0];
  const int*   ei = (const int*)d_in[1];
  const float* W1 = (const float*)d_in[2];
  const float* b1 = (const float*)d_in[3];
  const float* W2 = (const float*)d_in[4];
  const float* b2 = (const float*)d_in[5];
  float* out = (float*)d_out;

  char* w = (char*)d_ws;
  auto alloc = [&](size_t bytes) {
    char* p = w;
    w += (bytes + 255) & ~(size_t)255;
    return p;
  };
  float* h      = (float*)alloc((size_t)Nn * OUT_F * 4);
  float* zA     = (float*)alloc((size_t)Nn * OUT_F * 4);
  float* zB     = (float*)alloc((size_t)Nn * OUT_F * 4);
  int*   cnt    = (int*)alloc((size_t)Nn * 4);
  float* dinv   = (float*)alloc((size_t)Nn * 4);
  int*   offs   = (int*)alloc((size_t)Nn * 4);
  int*   cursor = (int*)alloc((size_t)Nn * 4);
  int*   bsum   = (int*)alloc(1024);
  int*   flag   = (int*)alloc(256);
  int*   nbr    = (int*)alloc((size_t)Ee * 4);
  float* wv     = (float*)alloc((size_t)Ee * 4);

  hipMemsetAsync(cnt, 0, (size_t)Nn * 4, stream);
  detect_k<<<1, 64, 0, stream>>>(ei, flag);
  mlp_k<<<(Nn + 63) / 64, 256, 0, stream>>>(x, W1, b1, W2, b2, h, Nn);
  hist_k<<<(Ee + 255) / 256, 256, 0, stream>>>(ei, cnt, flag, Ee);
  dinv_k<<<(Nn + 255) / 256, 256, 0, stream>>>(cnt, dinv, Nn);
  int nb = (Nn + 1023) / 1024;
  scan_blocks<<<nb, 256, 0, stream>>>(cnt, offs, bsum, Nn);
  scan_top<<<1, 128, 0, stream>>>(bsum, nb);
  scan_add<<<nb, 256, 0, stream>>>(offs, bsum, cursor, Nn);
  scatter_k<<<(Ee + 255) / 256, 256, 0, stream>>>(ei, dinv, cursor, nbr, wv, flag, Ee);

  const float* zin = h;
  for (int it = 0; it < 10; ++it) {
    float* zout = (it & 1) ? zB : zA;
    prop_k<<<(Nn + 15) / 16, 256, 0, stream>>>(zin, zout, h, offs, cnt, nbr, wv, dinv, Nn);
    zin = zout;
  }
  lsm_k<<<(Nn * OUT_F + 255) / 256, 256, 0, stream>>>(zin, out, Nn);
}

// Round 6
// 1194.439 us; speedup vs baseline: 1.1137x; 1.1137x over previous
//
#include <hip/hip_runtime.h>
#include <hip/hip_bf16.h>

#define IN_F 512
#define HID_F 256
#define OUT_F 16

typedef __bf16 bf8_t __attribute__((ext_vector_type(8)));
typedef float f4_t __attribute__((ext_vector_type(4)));
typedef unsigned short u16x4 __attribute__((ext_vector_type(4)));

__device__ __forceinline__ unsigned short f2b(float f) {
  union { float f; unsigned u; } a; a.f = f;
  unsigned u = a.u;
  u += 0x7fffu + ((u >> 16) & 1u);   // round-to-nearest-even bf16
  return (unsigned short)(u >> 16);
}

// Detect whether edge_index arrived as int64 (odd 32-bit words all zero) or int32.
__global__ void detect_k(const int* __restrict__ ei, int* __restrict__ flag) {
  if (threadIdx.x == 0 && blockIdx.x == 0) {
    int is64 = 1;
    for (int i = 0; i < 16; ++i)
      if (ei[2 * i + 1] != 0) is64 = 0;
    *flag = is64;
  }
}

// in-degree histogram over col (destination)
__global__ void hist_k(const int* __restrict__ ei, int* __restrict__ cnt,
                       const int* __restrict__ flag, int E_) {
  int e = blockIdx.x * 256 + threadIdx.x;
  if (e >= E_) return;
  int c;
  if (*flag) c = (int)((const long long*)ei)[E_ + e];   // coalesced 8B load
  else       c = ei[E_ + e];
  atomicAdd(&cnt[c], 1);
}

__global__ void dinv_k(const int* __restrict__ cnt, float* __restrict__ dinv, int n) {
  int i = blockIdx.x * 256 + threadIdx.x;
  if (i < n) dinv[i] = rsqrtf((float)(cnt[i] + 1));
}

// Fused MLP: h = relu(x@W1^T + b1) @ W2^T + b2; also writes zs0 = dinv*h.
__global__ __launch_bounds__(256) void mlp_k(
    const float* __restrict__ x, const float* __restrict__ W1,
    const float* __restrict__ b1, const float* __restrict__ W2,
    const float* __restrict__ b2, const float* __restrict__ dinv,
    float* __restrict__ h, float* __restrict__ zs0, int n) {
  __shared__ unsigned short a_sh[64][40];     // 64 nodes x 32 k (pad 8)
  __shared__ unsigned short w_sh[256][40];    // 256 hid x 32 k
  __shared__ unsigned short hid_sh[64][264];  // 64 nodes x 256 hid (pad 8)
  __shared__ unsigned short w2_sh[16][264];   // 16 out x 256 hid
  int tid = threadIdx.x;
  int node0 = blockIdx.x * 64;
  int wvid = tid >> 6;
  int lane = tid & 63;
  int row16 = lane & 15;
  int kg = lane >> 4;

  // stage W2 (16x256) -> bf16 LDS
  {
    int r = tid >> 4;
    int c0 = (tid & 15) * 16;
    const float* src = W2 + r * HID_F + c0;
    #pragma unroll
    for (int j = 0; j < 16; j += 4) {
      float4 v = *(const float4*)(src + j);
      u16x4 s = { f2b(v.x), f2b(v.y), f2b(v.z), f2b(v.w) };
      *(u16x4*)&w2_sh[r][c0 + j] = s;
    }
  }

  f4_t acc[4][4];
  #pragma unroll
  for (int mi = 0; mi < 4; ++mi)
    #pragma unroll
    for (int ni = 0; ni < 4; ++ni)
      acc[mi][ni] = (f4_t){0.f, 0.f, 0.f, 0.f};

  for (int kc = 0; kc < 16; ++kc) {
    int kb = kc * 32;
    __syncthreads();
    // stage A: x[node0..node0+63][kb..kb+31]
    {
      int r = tid >> 3;
      int c = (tid & 7) * 4;
      #pragma unroll
      for (int p = 0; p < 2; ++p) {
        int rr = p * 32 + r;
        int node = node0 + rr;
        float4 v;
        if (node < n) v = *(const float4*)(x + (size_t)node * IN_F + kb + c);
        else { v.x = 0.f; v.y = 0.f; v.z = 0.f; v.w = 0.f; }
        u16x4 s = { f2b(v.x), f2b(v.y), f2b(v.z), f2b(v.w) };
        *(u16x4*)&a_sh[rr][c] = s;
      }
    }
    // stage W1: W1[0..255][kb..kb+31]
    {
      int r = tid >> 3;
      int c = (tid & 7) * 4;
      #pragma unroll
      for (int p = 0; p < 8; ++p) {
        int rr = p * 32 + r;
        float4 v = *(const float4*)(W1 + (size_t)rr * IN_F + kb + c);
        u16x4 s = { f2b(v.x), f2b(v.y), f2b(v.z), f2b(v.w) };
        *(u16x4*)&w_sh[rr][c] = s;
      }
    }
    __syncthreads();
    bf8_t af[4], bfr[4];
    #pragma unroll
    for (int mi = 0; mi < 4; ++mi)
      af[mi] = *(const bf8_t*)&a_sh[mi * 16 + row16][kg * 8];
    #pragma unroll
    for (int ni = 0; ni < 4; ++ni)
      bfr[ni] = *(const bf8_t*)&w_sh[wvid * 64 + ni * 16 + row16][kg * 8];
    #pragma unroll
    for (int mi = 0; mi < 4; ++mi)
      #pragma unroll
      for (int ni = 0; ni < 4; ++ni)
        acc[mi][ni] = __builtin_amdgcn_mfma_f32_16x16x32_bf16(af[mi], bfr[ni], acc[mi][ni], 0, 0, 0);
  }
  __syncthreads();
  // epilogue 1: +b1, relu, -> hid_sh bf16.  C/D layout: col=lane&15, row=kg*4+r
  #pragma unroll
  for (int mi = 0; mi < 4; ++mi) {
    #pragma unroll
    for (int ni = 0; ni < 4; ++ni) {
      int col = wvid * 64 + ni * 16 + row16;
      float bias = b1[col];
      #pragma unroll
      for (int r = 0; r < 4; ++r) {
        int nl = mi * 16 + kg * 4 + r;
        float v = acc[mi][ni][r] + bias;
        v = fmaxf(v, 0.f);
        hid_sh[nl][col] = f2b(v);
      }
    }
  }
  __syncthreads();
  // GEMM2: each wave does 16 nodes x 16 out, K=256
  f4_t acc2 = (f4_t){0.f, 0.f, 0.f, 0.f};
  #pragma unroll
  for (int kc = 0; kc < 8; ++kc) {
    bf8_t a2  = *(const bf8_t*)&hid_sh[wvid * 16 + row16][kc * 32 + kg * 8];
    bf8_t b2f = *(const bf8_t*)&w2_sh[row16][kc * 32 + kg * 8];
    acc2 = __builtin_amdgcn_mfma_f32_16x16x32_bf16(a2, b2f, acc2, 0, 0, 0);
  }
  float bias2 = b2[row16];
  #pragma unroll
  for (int r = 0; r < 4; ++r) {
    int nl = wvid * 16 + kg * 4 + r;
    int node = node0 + nl;
    if (node < n) {
      float v = acc2[r] + bias2;
      h[(size_t)node * OUT_F + row16] = v;
      zs0[(size_t)node * OUT_F + row16] = dinv[node] * v;
    }
  }
}

// block-level exclusive scan (1024 elems/block, 4/thread)
__global__ void scan_blocks(const int* __restrict__ cnt, int* __restrict__ offs,
                            int* __restrict__ bsum, int n) {
  __shared__ int wsum[4];
  int tid = threadIdx.x;
  int base = blockIdx.x * 1024 + tid * 4;
  int v0 = (base + 0 < n) ? cnt[base + 0] : 0;
  int v1 = (base + 1 < n) ? cnt[base + 1] : 0;
  int v2 = (base + 2 < n) ? cnt[base + 2] : 0;
  int v3 = (base + 3 < n) ? cnt[base + 3] : 0;
  int tsum = v0 + v1 + v2 + v3;
  int lane = tid & 63, wv = tid >> 6;
  int inc = tsum;
  #pragma unroll
  for (int off = 1; off < 64; off <<= 1) {
    int t = __shfl_up(inc, off, 64);
    if (lane >= off) inc += t;
  }
  if (lane == 63) wsum[wv] = inc;
  __syncthreads();
  int add = 0;
  #pragma unroll
  for (int j = 0; j < 4; ++j)
    if (j < wv) add += wsum[j];
  int ex = add + inc - tsum;
  if (base + 0 < n) offs[base + 0] = ex;
  if (base + 1 < n) offs[base + 1] = ex + v0;
  if (base + 2 < n) offs[base + 2] = ex + v0 + v1;
  if (base + 3 < n) offs[base + 3] = ex + v0 + v1 + v2;
  if (tid == 255) bsum[blockIdx.x] = add + inc;
}

// exclusive scan of block sums (nb <= 128), one block of 128 threads
__global__ void scan_top(int* __restrict__ bsum, int nb) {
  __shared__ int w0;
  int tid = threadIdx.x;
  int v = (tid < nb) ? bsum[tid] : 0;
  int inc = v;
  #pragma unroll
  for (int off = 1; off < 64; off <<= 1) {
    int t = __shfl_up(inc, off, 64);
    if ((tid & 63) >= off) inc += t;
  }
  if (tid == 63) w0 = inc;
  __syncthreads();
  int ex = inc - v + ((tid >= 64) ? w0 : 0);
  if (tid < nb) bsum[tid] = ex;
}

__global__ void scan_add(int* __restrict__ offs, const int* __restrict__ bsum,
                         int* __restrict__ cursor, int n) {
  int base = blockIdx.x * 1024 + threadIdx.x * 4;
  int b = bsum[blockIdx.x];
  #pragma unroll
  for (int j = 0; j < 4; ++j) {
    int i = base + j;
    if (i < n) { int v = offs[i] + b; offs[i] = v; cursor[i] = v; }
  }
}

// scatter edges into CSR (by destination) — neighbor index only (no weights)
__global__ void scatter_k(const int* __restrict__ ei, int* __restrict__ cursor,
                          int* __restrict__ nbr, const int* __restrict__ flag, int E_) {
  int e = blockIdx.x * 256 + threadIdx.x;
  if (e >= E_) return;
  int r, c;
  if (*flag) {
    const long long* e64 = (const long long*)ei;
    r = (int)e64[e];
    c = (int)e64[E_ + e];
  } else {
    r = ei[e];
    c = ei[E_ + e];
  }
  int pos = atomicAdd(&cursor[c], 1);
  nbr[pos] = r;
}

// one APPNP iteration on the pre-scaled iterate zs = dinv*z:
//   z_new[i]  = 0.9 * dinv[i] * (zs_self + sum_{j in in(i)} zs[j]) + 0.1*h[i]
//   zs_out[i] = dinv[i] * z_new[i]
// If fin != 0, apply log_softmax over the 16 outputs and write `out` instead.
__global__ __launch_bounds__(256) void prop_k(
    const float* __restrict__ zs_in, float* __restrict__ zs_out,
    const float* __restrict__ h, const int* __restrict__ offs,
    const int* __restrict__ cnt, const int* __restrict__ nbr,
    const float* __restrict__ dinv, float* __restrict__ out, int fin, int n) {
  int tid = threadIdx.x;
  int node = blockIdx.x * 16 + (tid >> 4);
  int lane = tid & 15;
  if (node >= n) return;
  float di = dinv[node];
  int base = node * OUT_F + lane;
  float a0 = zs_in[base];   // self loop term
  float a1 = 0.f;
  int s = offs[node];
  int end = s + cnt[node];
  int e = s;
  for (; e + 4 <= end; e += 4) {
    int j0 = nbr[e], j1 = nbr[e + 1], j2 = nbr[e + 2], j3 = nbr[e + 3];
    a0 += zs_in[j0 * OUT_F + lane];
    a1 += zs_in[j1 * OUT_F + lane];
    a0 += zs_in[j2 * OUT_F + lane];
    a1 += zs_in[j3 * OUT_F + lane];
  }
  for (; e < end; ++e) a0 += zs_in[nbr[e] * OUT_F + lane];
  float z = 0.9f * di * (a0 + a1) + 0.1f * h[base];
  if (!fin) {
    zs_out[base] = di * z;
  } else {
    float m = z;
    #pragma unroll
    for (int sdx = 8; sdx; sdx >>= 1) m = fmaxf(m, __shfl_xor(m, sdx, 16));
    float ex = expf(z - m);
    float t = ex;
    #pragma unroll
    for (int sdx = 8; sdx; sdx >>= 1) t += __shfl_xor(t, sdx, 16);
    out[base] = z - m - logf(t);
  }
}

extern "C" void kernel_launch(void* const* d_in, const int* in_sizes, int n_in,
                              void* d_out, int out_size, void* d_ws, size_t ws_size,
                              hipStream_t stream) {
  const int Nn = in_sizes[0] / IN_F;
  const int Ee = in_sizes[1] / 2;
  const float* x  = (const float*)d_in[0];
  const int*   ei = (const int*)d_in[1];
  const float* W1 = (const float*)d_in[2];
  const float* b1 = (const float*)d_in[3];
  const float* W2 = (const float*)d_in[4];
  const float* b2 = (const float*)d_in[5];
  float* out = (float*)d_out;

  char* w = (char*)d_ws;
  auto alloc = [&](size_t bytes) {
    char* p = w;
    w += (bytes + 255) & ~(size_t)255;
    return p;
  };
  float* h      = (float*)alloc((size_t)Nn * OUT_F * 4);
  float* zsA    = (float*)alloc((size_t)Nn * OUT_F * 4);
  float* zsB    = (float*)alloc((size_t)Nn * OUT_F * 4);
  int*   cnt    = (int*)alloc((size_t)Nn * 4);
  float* dinv   = (float*)alloc((size_t)Nn * 4);
  int*   offs   = (int*)alloc((size_t)Nn * 4);
  int*   cursor = (int*)alloc((size_t)Nn * 4);
  int*   bsum   = (int*)alloc(1024);
  int*   flag   = (int*)alloc(256);
  int*   nbr    = (int*)alloc((size_t)Ee * 4);

  hipMemsetAsync(cnt, 0, (size_t)Nn * 4, stream);
  detect_k<<<1, 64, 0, stream>>>(ei, flag);
  hist_k<<<(Ee + 255) / 256, 256, 0, stream>>>(ei, cnt, flag, Ee);
  dinv_k<<<(Nn + 255) / 256, 256, 0, stream>>>(cnt, dinv, Nn);
  mlp_k<<<(Nn + 63) / 64, 256, 0, stream>>>(x, W1, b1, W2, b2, dinv, h, zsA, Nn);
  int nb = (Nn + 1023) / 1024;
  scan_blocks<<<nb, 256, 0, stream>>>(cnt, offs, bsum, Nn);
  scan_top<<<1, 128, 0, stream>>>(bsum, nb);
  scan_add<<<nb, 256, 0, stream>>>(offs, bsum, cursor, Nn);
  scatter_k<<<(Ee + 255) / 256, 256, 0, stream>>>(ei, cursor, nbr, flag, Ee);

  for (int it = 0; it < 10; ++it) {
    const float* zin = (it & 1) ? zsB : zsA;
    float* zout = (it & 1) ? zsA : zsB;
    int fin = (it == 9) ? 1 : 0;
    prop_k<<<(Nn + 15) / 16, 256, 0, stream>>>(zin, zout, h, offs, cnt, nbr,
                                               dinv, out, fin, Nn);
  }
}

// Round 7
// 1134.034 us; speedup vs baseline: 1.1730x; 1.0533x over previous
//
#include <hip/hip_runtime.h>
#include <hip/hip_bf16.h>

#define IN_F 512
#define HID_F 256
#define OUT_F 16
#define PHASE_SH 14   // dest-range phase size 16384 nodes -> ~2.1 MB write window (< 4 MB L2/XCD)

typedef __bf16 bf8_t __attribute__((ext_vector_type(8)));
typedef float f4_t __attribute__((ext_vector_type(4)));
typedef unsigned short u16x4 __attribute__((ext_vector_type(4)));

__device__ __forceinline__ unsigned short f2b(float f) {
  union { float f; unsigned u; } a; a.f = f;
  unsigned u = a.u;
  u += 0x7fffu + ((u >> 16) & 1u);   // round-to-nearest-even bf16
  return (unsigned short)(u >> 16);
}

// Detect whether edge_index arrived as int64 (odd 32-bit words all zero) or int32.
__global__ void detect_k(const int* __restrict__ ei, int* __restrict__ flag) {
  if (threadIdx.x == 0 && blockIdx.x == 0) {
    int is64 = 1;
    for (int i = 0; i < 16; ++i)
      if (ei[2 * i + 1] != 0) is64 = 0;
    *flag = is64;
  }
}

// Convert edge list to packed int32 row/col arrays (one coalesced pass).
__global__ void cvt_k(const int* __restrict__ ei, int* __restrict__ row32,
                      int* __restrict__ col32, const int* __restrict__ flag, int E_) {
  int e = blockIdx.x * 256 + threadIdx.x;
  if (e >= E_) return;
  if (*flag) {
    const long long* e64 = (const long long*)ei;
    row32[e] = (int)e64[e];
    col32[e] = (int)e64[E_ + e];
  } else {
    row32[e] = ei[e];
    col32[e] = ei[E_ + e];
  }
}

// in-degree histogram over col (destination)
__global__ void hist_k(const int* __restrict__ col32, int* __restrict__ cnt, int E_) {
  int e = blockIdx.x * 256 + threadIdx.x;
  if (e >= E_) return;
  atomicAdd(&cnt[col32[e]], 1);
}

__global__ void dinv_k(const int* __restrict__ cnt, float* __restrict__ dinv, int n) {
  int i = blockIdx.x * 256 + threadIdx.x;
  if (i < n) dinv[i] = rsqrtf((float)(cnt[i] + 1));
}

// Fused MLP: h = relu(x@W1^T + b1) @ W2^T + b2; also writes zs0 = dinv*h.
__global__ __launch_bounds__(256) void mlp_k(
    const float* __restrict__ x, const float* __restrict__ W1,
    const float* __restrict__ b1, const float* __restrict__ W2,
    const float* __restrict__ b2, const float* __restrict__ dinv,
    float* __restrict__ h, float* __restrict__ zs0, int n) {
  __shared__ unsigned short a_sh[64][40];     // 64 nodes x 32 k (pad 8)
  __shared__ unsigned short w_sh[256][40];    // 256 hid x 32 k
  __shared__ unsigned short hid_sh[64][264];  // 64 nodes x 256 hid (pad 8)
  __shared__ unsigned short w2_sh[16][264];   // 16 out x 256 hid
  int tid = threadIdx.x;
  int node0 = blockIdx.x * 64;
  int wvid = tid >> 6;
  int lane = tid & 63;
  int row16 = lane & 15;
  int kg = lane >> 4;

  // stage W2 (16x256) -> bf16 LDS
  {
    int r = tid >> 4;
    int c0 = (tid & 15) * 16;
    const float* src = W2 + r * HID_F + c0;
    #pragma unroll
    for (int j = 0; j < 16; j += 4) {
      float4 v = *(const float4*)(src + j);
      u16x4 s = { f2b(v.x), f2b(v.y), f2b(v.z), f2b(v.w) };
      *(u16x4*)&w2_sh[r][c0 + j] = s;
    }
  }

  f4_t acc[4][4];
  #pragma unroll
  for (int mi = 0; mi < 4; ++mi)
    #pragma unroll
    for (int ni = 0; ni < 4; ++ni)
      acc[mi][ni] = (f4_t){0.f, 0.f, 0.f, 0.f};

  for (int kc = 0; kc < 16; ++kc) {
    int kb = kc * 32;
    __syncthreads();
    // stage A: x[node0..node0+63][kb..kb+31]
    {
      int r = tid >> 3;
      int c = (tid & 7) * 4;
      #pragma unroll
      for (int p = 0; p < 2; ++p) {
        int rr = p * 32 + r;
        int node = node0 + rr;
        float4 v;
        if (node < n) v = *(const float4*)(x + (size_t)node * IN_F + kb + c);
        else { v.x = 0.f; v.y = 0.f; v.z = 0.f; v.w = 0.f; }
        u16x4 s = { f2b(v.x), f2b(v.y), f2b(v.z), f2b(v.w) };
        *(u16x4*)&a_sh[rr][c] = s;
      }
    }
    // stage W1: W1[0..255][kb..kb+31]
    {
      int r = tid >> 3;
      int c = (tid & 7) * 4;
      #pragma unroll
      for (int p = 0; p < 8; ++p) {
        int rr = p * 32 + r;
        float4 v = *(const float4*)(W1 + (size_t)rr * IN_F + kb + c);
        u16x4 s = { f2b(v.x), f2b(v.y), f2b(v.z), f2b(v.w) };
        *(u16x4*)&w_sh[rr][c] = s;
      }
    }
    __syncthreads();
    bf8_t af[4], bfr[4];
    #pragma unroll
    for (int mi = 0; mi < 4; ++mi)
      af[mi] = *(const bf8_t*)&a_sh[mi * 16 + row16][kg * 8];
    #pragma unroll
    for (int ni = 0; ni < 4; ++ni)
      bfr[ni] = *(const bf8_t*)&w_sh[wvid * 64 + ni * 16 + row16][kg * 8];
    #pragma unroll
    for (int mi = 0; mi < 4; ++mi)
      #pragma unroll
      for (int ni = 0; ni < 4; ++ni)
        acc[mi][ni] = __builtin_amdgcn_mfma_f32_16x16x32_bf16(af[mi], bfr[ni], acc[mi][ni], 0, 0, 0);
  }
  __syncthreads();
  // epilogue 1: +b1, relu, -> hid_sh bf16.  C/D layout: col=lane&15, row=kg*4+r
  #pragma unroll
  for (int mi = 0; mi < 4; ++mi) {
    #pragma unroll
    for (int ni = 0; ni < 4; ++ni) {
      int col = wvid * 64 + ni * 16 + row16;
      float bias = b1[col];
      #pragma unroll
      for (int r = 0; r < 4; ++r) {
        int nl = mi * 16 + kg * 4 + r;
        float v = acc[mi][ni][r] + bias;
        v = fmaxf(v, 0.f);
        hid_sh[nl][col] = f2b(v);
      }
    }
  }
  __syncthreads();
  // GEMM2: each wave does 16 nodes x 16 out, K=256
  f4_t acc2 = (f4_t){0.f, 0.f, 0.f, 0.f};
  #pragma unroll
  for (int kc = 0; kc < 8; ++kc) {
    bf8_t a2  = *(const bf8_t*)&hid_sh[wvid * 16 + row16][kc * 32 + kg * 8];
    bf8_t b2f = *(const bf8_t*)&w2_sh[row16][kc * 32 + kg * 8];
    acc2 = __builtin_amdgcn_mfma_f32_16x16x32_bf16(a2, b2f, acc2, 0, 0, 0);
  }
  float bias2 = b2[row16];
  #pragma unroll
  for (int r = 0; r < 4; ++r) {
    int nl = wvid * 16 + kg * 4 + r;
    int node = node0 + nl;
    if (node < n) {
      float v = acc2[r] + bias2;
      h[(size_t)node * OUT_F + row16] = v;
      zs0[(size_t)node * OUT_F + row16] = dinv[node] * v;
    }
  }
}

// block-level exclusive scan (1024 elems/block, 4/thread)
__global__ void scan_blocks(const int* __restrict__ cnt, int* __restrict__ offs,
                            int* __restrict__ bsum, int n) {
  __shared__ int wsum[4];
  int tid = threadIdx.x;
  int base = blockIdx.x * 1024 + tid * 4;
  int v0 = (base + 0 < n) ? cnt[base + 0] : 0;
  int v1 = (base + 1 < n) ? cnt[base + 1] : 0;
  int v2 = (base + 2 < n) ? cnt[base + 2] : 0;
  int v3 = (base + 3 < n) ? cnt[base + 3] : 0;
  int tsum = v0 + v1 + v2 + v3;
  int lane = tid & 63, wv = tid >> 6;
  int inc = tsum;
  #pragma unroll
  for (int off = 1; off < 64; off <<= 1) {
    int t = __shfl_up(inc, off, 64);
    if (lane >= off) inc += t;
  }
  if (lane == 63) wsum[wv] = inc;
  __syncthreads();
  int add = 0;
  #pragma unroll
  for (int j = 0; j < 4; ++j)
    if (j < wv) add += wsum[j];
  int ex = add + inc - tsum;
  if (base + 0 < n) offs[base + 0] = ex;
  if (base + 1 < n) offs[base + 1] = ex + v0;
  if (base + 2 < n) offs[base + 2] = ex + v0 + v1;
  if (base + 3 < n) offs[base + 3] = ex + v0 + v1 + v2;
  if (tid == 255) bsum[blockIdx.x] = add + inc;
}

// exclusive scan of block sums (nb <= 128), one block of 128 threads
__global__ void scan_top(int* __restrict__ bsum, int nb) {
  __shared__ int w0;
  int tid = threadIdx.x;
  int v = (tid < nb) ? bsum[tid] : 0;
  int inc = v;
  #pragma unroll
  for (int off = 1; off < 64; off <<= 1) {
    int t = __shfl_up(inc, off, 64);
    if ((tid & 63) >= off) inc += t;
  }
  if (tid == 63) w0 = inc;
  __syncthreads();
  int ex = inc - v + ((tid >= 64) ? w0 : 0);
  if (tid < nb) bsum[tid] = ex;
}

__global__ void scan_add(int* __restrict__ offs, const int* __restrict__ bsum,
                         int* __restrict__ cursor, int n) {
  int base = blockIdx.x * 1024 + threadIdx.x * 4;
  int b = bsum[blockIdx.x];
  #pragma unroll
  for (int j = 0; j < 4; ++j) {
    int i = base + j;
    if (i < n) { int v = offs[i] + b; offs[i] = v; cursor[i] = v; }
  }
}

// Phased CSR scatter: phase p handles dests in [p<<PHASE_SH, (p+1)<<PHASE_SH).
// Write window per phase ~2 MB -> stays L2-resident, lines fill before eviction.
__global__ __launch_bounds__(256) void scatter_p(
    const int* __restrict__ row32, const int* __restrict__ col32,
    int* __restrict__ cursor, int* __restrict__ nbr, int E_, int nph) {
  int gsz = gridDim.x * 256;
  int g0 = blockIdx.x * 256 + threadIdx.x;
  for (int p = 0; p < nph; ++p) {
    for (int e = g0; e < E_; e += gsz) {
      int c = col32[e];
      if ((c >> PHASE_SH) == p) {
        int pos = atomicAdd(&cursor[c], 1);
        nbr[pos] = row32[e];
      }
    }
  }
}

// one APPNP iteration on the pre-scaled iterate zs = dinv*z:
//   z_new[i]  = 0.9 * dinv[i] * (zs_self + sum_{j in in(i)} zs[j]) + 0.1*h[i]
//   zs_out[i] = dinv[i] * z_new[i]
// If fin != 0, apply log_softmax over the 16 outputs and write `out` instead.
__global__ __launch_bounds__(256) void prop_k(
    const float* __restrict__ zs_in, float* __restrict__ zs_out,
    const float* __restrict__ h, const int* __restrict__ offs,
    const int* __restrict__ cnt, const int* __restrict__ nbr,
    const float* __restrict__ dinv, float* __restrict__ out, int fin, int n) {
  int tid = threadIdx.x;
  int node = blockIdx.x * 16 + (tid >> 4);
  int lane = tid & 15;
  if (node >= n) return;
  float di = dinv[node];
  int base = node * OUT_F + lane;
  float a0 = zs_in[base];   // self loop term
  float a1 = 0.f;
  int s = offs[node];
  int end = s + cnt[node];
  int e = s;
  for (; e + 4 <= end; e += 4) {
    int j0 = nbr[e], j1 = nbr[e + 1], j2 = nbr[e + 2], j3 = nbr[e + 3];
    a0 += zs_in[j0 * OUT_F + lane];
    a1 += zs_in[j1 * OUT_F + lane];
    a0 += zs_in[j2 * OUT_F + lane];
    a1 += zs_in[j3 * OUT_F + lane];
  }
  for (; e < end; ++e) a0 += zs_in[nbr[e] * OUT_F + lane];
  float z = 0.9f * di * (a0 + a1) + 0.1f * h[base];
  if (!fin) {
    zs_out[base] = di * z;
  } else {
    float m = z;
    #pragma unroll
    for (int sdx = 8; sdx; sdx >>= 1) m = fmaxf(m, __shfl_xor(m, sdx, 16));
    float ex = expf(z - m);
    float t = ex;
    #pragma unroll
    for (int sdx = 8; sdx; sdx >>= 1) t += __shfl_xor(t, sdx, 16);
    out[base] = z - m - logf(t);
  }
}

extern "C" void kernel_launch(void* const* d_in, const int* in_sizes, int n_in,
                              void* d_out, int out_size, void* d_ws, size_t ws_size,
                              hipStream_t stream) {
  const int Nn = in_sizes[0] / IN_F;
  const int Ee = in_sizes[1] / 2;
  const float* x  = (const float*)d_in[0];
  const int*   ei = (const int*)d_in[1];
  const float* W1 = (const float*)d_in[2];
  const float* b1 = (const float*)d_in[3];
  const float* W2 = (const float*)d_in[4];
  const float* b2 = (const float*)d_in[5];
  float* out = (float*)d_out;

  char* w = (char*)d_ws;
  auto alloc = [&](size_t bytes) {
    char* p = w;
    w += (bytes + 255) & ~(size_t)255;
    return p;
  };
  float* h      = (float*)alloc((size_t)Nn * OUT_F * 4);
  float* zsA    = (float*)alloc((size_t)Nn * OUT_F * 4);
  float* zsB    = (float*)alloc((size_t)Nn * OUT_F * 4);
  int*   cnt    = (int*)alloc((size_t)Nn * 4);
  float* dinv   = (float*)alloc((size_t)Nn * 4);
  int*   offs   = (int*)alloc((size_t)Nn * 4);
  int*   cursor = (int*)alloc((size_t)Nn * 4);
  int*   bsum   = (int*)alloc(1024);
  int*   flag   = (int*)alloc(256);
  int*   nbr    = (int*)alloc((size_t)Ee * 4);
  int*   col32  = (int*)alloc((size_t)Ee * 4);
  // row32 aliases [h | zsA]: dead before mlp_k writes h/zsA (mlp runs after scatter_p).
  int*   row32  = (int*)h;

  hipMemsetAsync(cnt, 0, (size_t)Nn * 4, stream);
  detect_k<<<1, 64, 0, stream>>>(ei, flag);
  cvt_k<<<(Ee + 255) / 256, 256, 0, stream>>>(ei, row32, col32, flag, Ee);
  hist_k<<<(Ee + 255) / 256, 256, 0, stream>>>(col32, cnt, Ee);
  dinv_k<<<(Nn + 255) / 256, 256, 0, stream>>>(cnt, dinv, Nn);
  int nb = (Nn + 1023) / 1024;
  scan_blocks<<<nb, 256, 0, stream>>>(cnt, offs, bsum, Nn);
  scan_top<<<1, 128, 0, stream>>>(bsum, nb);
  scan_add<<<nb, 256, 0, stream>>>(offs, bsum, cursor, Nn);
  int nph = (Nn + (1 << PHASE_SH) - 1) >> PHASE_SH;
  scatter_p<<<1024, 256, 0, stream>>>(row32, col32, cursor, nbr, Ee, nph);
  // mlp AFTER scatter so row32's alias region (h, zsA) is free during the scatter
  mlp_k<<<(Nn + 63) / 64, 256, 0, stream>>>(x, W1, b1, W2, b2, dinv, h, zsA, Nn);

  for (int it = 0; it < 10; ++it) {
    const float* zin = (it & 1) ? zsB : zsA;
    float* zout = (it & 1) ? zsA : zsB;
    int fin = (it == 9) ? 1 : 0;
    prop_k<<<(Nn + 15) / 16, 256, 0, stream>>>(zin, zout, h, offs, cnt, nbr,
                                               dinv, out, fin, Nn);
  }
}

// Round 8
// 1089.717 us; speedup vs baseline: 1.2207x; 1.0407x over previous
//
#include <hip/hip_runtime.h>
#include <hip/hip_bf16.h>

#define IN_F 512
#define HID_F 256
#define OUT_F 16
#define PHASE_DIV 12512   // dests per phase; 8 phases for N=100000; window ~1.6MB (< 4MB L2/XCD)
#define NXCD 8

typedef __bf16 bf8_t __attribute__((ext_vector_type(8)));
typedef float f4_t __attribute__((ext_vector_type(4)));
typedef unsigned short u16x4 __attribute__((ext_vector_type(4)));

__device__ __forceinline__ unsigned short f2b(float f) {
  union { float f; unsigned u; } a; a.f = f;
  unsigned u = a.u;
  u += 0x7fffu + ((u >> 16) & 1u);   // round-to-nearest-even bf16
  return (unsigned short)(u >> 16);
}

// Detect whether edge_index arrived as int64 (odd 32-bit words all zero) or int32.
__global__ void detect_k(const int* __restrict__ ei, int* __restrict__ flag) {
  if (threadIdx.x == 0 && blockIdx.x == 0) {
    int is64 = 1;
    for (int i = 0; i < 16; ++i)
      if (ei[2 * i + 1] != 0) is64 = 0;
    *flag = is64;
  }
}

// Convert edge list to packed int32 row/col arrays + fused in-degree histogram.
__global__ void cvt_k(const int* __restrict__ ei, int* __restrict__ row32,
                      int* __restrict__ col32, int* __restrict__ cnt,
                      const int* __restrict__ flag, int E_) {
  int e = blockIdx.x * 256 + threadIdx.x;
  if (e >= E_) return;
  int r, c;
  if (*flag) {
    const long long* e64 = (const long long*)ei;
    r = (int)e64[e];
    c = (int)e64[E_ + e];
  } else {
    r = ei[e];
    c = ei[E_ + e];
  }
  row32[e] = r;
  col32[e] = c;
  atomicAdd(&cnt[c], 1);
}

__global__ void dinv_k(const int* __restrict__ cnt, float* __restrict__ dinv, int n) {
  int i = blockIdx.x * 256 + threadIdx.x;
  if (i < n) dinv[i] = rsqrtf((float)(cnt[i] + 1));
}

// Fused MLP: h = relu(x@W1^T + b1) @ W2^T + b2; also writes zs0 = dinv*h.
__global__ __launch_bounds__(256) void mlp_k(
    const float* __restrict__ x, const float* __restrict__ W1,
    const float* __restrict__ b1, const float* __restrict__ W2,
    const float* __restrict__ b2, const float* __restrict__ dinv,
    float* __restrict__ h, float* __restrict__ zs0, int n) {
  __shared__ unsigned short a_sh[64][40];     // 64 nodes x 32 k (pad 8)
  __shared__ unsigned short w_sh[256][40];    // 256 hid x 32 k
  __shared__ unsigned short hid_sh[64][264];  // 64 nodes x 256 hid (pad 8)
  __shared__ unsigned short w2_sh[16][264];   // 16 out x 256 hid
  int tid = threadIdx.x;
  int node0 = blockIdx.x * 64;
  int wvid = tid >> 6;
  int lane = tid & 63;
  int row16 = lane & 15;
  int kg = lane >> 4;

  // stage W2 (16x256) -> bf16 LDS
  {
    int r = tid >> 4;
    int c0 = (tid & 15) * 16;
    const float* src = W2 + r * HID_F + c0;
    #pragma unroll
    for (int j = 0; j < 16; j += 4) {
      float4 v = *(const float4*)(src + j);
      u16x4 s = { f2b(v.x), f2b(v.y), f2b(v.z), f2b(v.w) };
      *(u16x4*)&w2_sh[r][c0 + j] = s;
    }
  }

  f4_t acc[4][4];
  #pragma unroll
  for (int mi = 0; mi < 4; ++mi)
    #pragma unroll
    for (int ni = 0; ni < 4; ++ni)
      acc[mi][ni] = (f4_t){0.f, 0.f, 0.f, 0.f};

  for (int kc = 0; kc < 16; ++kc) {
    int kb = kc * 32;
    __syncthreads();
    // stage A: x[node0..node0+63][kb..kb+31]
    {
      int r = tid >> 3;
      int c = (tid & 7) * 4;
      #pragma unroll
      for (int p = 0; p < 2; ++p) {
        int rr = p * 32 + r;
        int node = node0 + rr;
        float4 v;
        if (node < n) v = *(const float4*)(x + (size_t)node * IN_F + kb + c);
        else { v.x = 0.f; v.y = 0.f; v.z = 0.f; v.w = 0.f; }
        u16x4 s = { f2b(v.x), f2b(v.y), f2b(v.z), f2b(v.w) };
        *(u16x4*)&a_sh[rr][c] = s;
      }
    }
    // stage W1: W1[0..255][kb..kb+31]
    {
      int r = tid >> 3;
      int c = (tid & 7) * 4;
      #pragma unroll
      for (int p = 0; p < 8; ++p) {
        int rr = p * 32 + r;
        float4 v = *(const float4*)(W1 + (size_t)rr * IN_F + kb + c);
        u16x4 s = { f2b(v.x), f2b(v.y), f2b(v.z), f2b(v.w) };
        *(u16x4*)&w_sh[rr][c] = s;
      }
    }
    __syncthreads();
    bf8_t af[4], bfr[4];
    #pragma unroll
    for (int mi = 0; mi < 4; ++mi)
      af[mi] = *(const bf8_t*)&a_sh[mi * 16 + row16][kg * 8];
    #pragma unroll
    for (int ni = 0; ni < 4; ++ni)
      bfr[ni] = *(const bf8_t*)&w_sh[wvid * 64 + ni * 16 + row16][kg * 8];
    #pragma unroll
    for (int mi = 0; mi < 4; ++mi)
      #pragma unroll
      for (int ni = 0; ni < 4; ++ni)
        acc[mi][ni] = __builtin_amdgcn_mfma_f32_16x16x32_bf16(af[mi], bfr[ni], acc[mi][ni], 0, 0, 0);
  }
  __syncthreads();
  // epilogue 1: +b1, relu, -> hid_sh bf16.  C/D layout: col=lane&15, row=kg*4+r
  #pragma unroll
  for (int mi = 0; mi < 4; ++mi) {
    #pragma unroll
    for (int ni = 0; ni < 4; ++ni) {
      int col = wvid * 64 + ni * 16 + row16;
      float bias = b1[col];
      #pragma unroll
      for (int r = 0; r < 4; ++r) {
        int nl = mi * 16 + kg * 4 + r;
        float v = acc[mi][ni][r] + bias;
        v = fmaxf(v, 0.f);
        hid_sh[nl][col] = f2b(v);
      }
    }
  }
  __syncthreads();
  // GEMM2: each wave does 16 nodes x 16 out, K=256
  f4_t acc2 = (f4_t){0.f, 0.f, 0.f, 0.f};
  #pragma unroll
  for (int kc = 0; kc < 8; ++kc) {
    bf8_t a2  = *(const bf8_t*)&hid_sh[wvid * 16 + row16][kc * 32 + kg * 8];
    bf8_t b2f = *(const bf8_t*)&w2_sh[row16][kc * 32 + kg * 8];
    acc2 = __builtin_amdgcn_mfma_f32_16x16x32_bf16(a2, b2f, acc2, 0, 0, 0);
  }
  float bias2 = b2[row16];
  #pragma unroll
  for (int r = 0; r < 4; ++r) {
    int nl = wvid * 16 + kg * 4 + r;
    int node = node0 + nl;
    if (node < n) {
      float v = acc2[r] + bias2;
      h[(size_t)node * OUT_F + row16] = v;
      zs0[(size_t)node * OUT_F + row16] = dinv[node] * v;
    }
  }
}

// block-level exclusive scan (1024 elems/block, 4/thread)
__global__ void scan_blocks(const int* __restrict__ cnt, int* __restrict__ offs,
                            int* __restrict__ bsum, int n) {
  __shared__ int wsum[4];
  int tid = threadIdx.x;
  int base = blockIdx.x * 1024 + tid * 4;
  int v0 = (base + 0 < n) ? cnt[base + 0] : 0;
  int v1 = (base + 1 < n) ? cnt[base + 1] : 0;
  int v2 = (base + 2 < n) ? cnt[base + 2] : 0;
  int v3 = (base + 3 < n) ? cnt[base + 3] : 0;
  int tsum = v0 + v1 + v2 + v3;
  int lane = tid & 63, wv = tid >> 6;
  int inc = tsum;
  #pragma unroll
  for (int off = 1; off < 64; off <<= 1) {
    int t = __shfl_up(inc, off, 64);
    if (lane >= off) inc += t;
  }
  if (lane == 63) wsum[wv] = inc;
  __syncthreads();
  int add = 0;
  #pragma unroll
  for (int j = 0; j < 4; ++j)
    if (j < wv) add += wsum[j];
  int ex = add + inc - tsum;
  if (base + 0 < n) offs[base + 0] = ex;
  if (base + 1 < n) offs[base + 1] = ex + v0;
  if (base + 2 < n) offs[base + 2] = ex + v0 + v1;
  if (base + 3 < n) offs[base + 3] = ex + v0 + v1 + v2;
  if (tid == 255) bsum[blockIdx.x] = add + inc;
}

// exclusive scan of block sums (nb <= 128), one block of 128 threads
__global__ void scan_top(int* __restrict__ bsum, int nb) {
  __shared__ int w0;
  int tid = threadIdx.x;
  int v = (tid < nb) ? bsum[tid] : 0;
  int inc = v;
  #pragma unroll
  for (int off = 1; off < 64; off <<= 1) {
    int t = __shfl_up(inc, off, 64);
    if ((tid & 63) >= off) inc += t;
  }
  if (tid == 63) w0 = inc;
  __syncthreads();
  int ex = inc - v + ((tid >= 64) ? w0 : 0);
  if (tid < nb) bsum[tid] = ex;
}

__global__ void scan_add(int* __restrict__ offs, const int* __restrict__ bsum,
                         int* __restrict__ cursor, int n) {
  int base = blockIdx.x * 1024 + threadIdx.x * 4;
  int b = bsum[blockIdx.x];
  #pragma unroll
  for (int j = 0; j < 4; ++j) {
    int i = base + j;
    if (i < n) { int v = offs[i] + b; offs[i] = v; cursor[i] = v; }
  }
}

// XCD-pinned phased CSR scatter. blockIdx%8 maps round-robin to XCDs (perf
// heuristic only); blocks in group g handle ONLY dests in phase(s) g, g+8, ...
// -> each phase's ~1.6MB nbr window is written by exactly one XCD, lines fill
// completely in its L2 before writeback. Correctness is blockIdx-based: every
// phase is claimed by construction regardless of the physical XCD mapping.
__global__ __launch_bounds__(256) void scatter_x(
    const int* __restrict__ row32, const int* __restrict__ col32,
    int* __restrict__ cursor, int* __restrict__ nbr, int E_, int nph) {
  int grp = blockIdx.x & (NXCD - 1);
  int bid = blockIdx.x >> 3;                 // index within group
  int nbk = gridDim.x >> 3;                  // blocks per group
  int stride = nbk * 256;
  for (int p = grp; p < nph; p += NXCD) {
    for (int e = bid * 256 + threadIdx.x; e < E_; e += stride) {
      int c = col32[e];
      if (c / PHASE_DIV == p) {
        int pos = atomicAdd(&cursor[c], 1);
        nbr[pos] = row32[e];
      }
    }
  }
}

// one APPNP iteration on the pre-scaled iterate zs = dinv*z:
//   z_new[i]  = 0.9 * dinv[i] * (zs_self + sum_{j in in(i)} zs[j]) + 0.1*h[i]
//   zs_out[i] = dinv[i] * z_new[i]
// If fin != 0, apply log_softmax over the 16 outputs and write `out` instead.
__global__ __launch_bounds__(256) void prop_k(
    const float* __restrict__ zs_in, float* __restrict__ zs_out,
    const float* __restrict__ h, const int* __restrict__ offs,
    const int* __restrict__ cnt, const int* __restrict__ nbr,
    const float* __restrict__ dinv, float* __restrict__ out, int fin, int n) {
  int tid = threadIdx.x;
  int node = blockIdx.x * 16 + (tid >> 4);
  int lane = tid & 15;
  if (node >= n) return;
  float di = dinv[node];
  int base = node * OUT_F + lane;
  float a0 = zs_in[base];   // self loop term
  float a1 = 0.f;
  int s = offs[node];
  int end = s + cnt[node];
  int e = s;
  for (; e + 4 <= end; e += 4) {
    int j0 = nbr[e], j1 = nbr[e + 1], j2 = nbr[e + 2], j3 = nbr[e + 3];
    a0 += zs_in[j0 * OUT_F + lane];
    a1 += zs_in[j1 * OUT_F + lane];
    a0 += zs_in[j2 * OUT_F + lane];
    a1 += zs_in[j3 * OUT_F + lane];
  }
  for (; e < end; ++e) a0 += zs_in[nbr[e] * OUT_F + lane];
  float z = 0.9f * di * (a0 + a1) + 0.1f * h[base];
  if (!fin) {
    zs_out[base] = di * z;
  } else {
    float m = z;
    #pragma unroll
    for (int sdx = 8; sdx; sdx >>= 1) m = fmaxf(m, __shfl_xor(m, sdx, 16));
    float ex = expf(z - m);
    float t = ex;
    #pragma unroll
    for (int sdx = 8; sdx; sdx >>= 1) t += __shfl_xor(t, sdx, 16);
    out[base] = z - m - logf(t);
  }
}

extern "C" void kernel_launch(void* const* d_in, const int* in_sizes, int n_in,
                              void* d_out, int out_size, void* d_ws, size_t ws_size,
                              hipStream_t stream) {
  const int Nn = in_sizes[0] / IN_F;
  const int Ee = in_sizes[1] / 2;
  const float* x  = (const float*)d_in[0];
  const int*   ei = (const int*)d_in[1];
  const float* W1 = (const float*)d_in[2];
  const float* b1 = (const float*)d_in[3];
  const float* W2 = (const float*)d_in[4];
  const float* b2 = (const float*)d_in[5];
  float* out = (float*)d_out;

  char* w = (char*)d_ws;
  auto alloc = [&](size_t bytes) {
    char* p = w;
    w += (bytes + 255) & ~(size_t)255;
    return p;
  };
  float* h      = (float*)alloc((size_t)Nn * OUT_F * 4);
  float* zsA    = (float*)alloc((size_t)Nn * OUT_F * 4);
  float* zsB    = (float*)alloc((size_t)Nn * OUT_F * 4);
  int*   cnt    = (int*)alloc((size_t)Nn * 4);
  float* dinv   = (float*)alloc((size_t)Nn * 4);
  int*   offs   = (int*)alloc((size_t)Nn * 4);
  int*   cursor = (int*)alloc((size_t)Nn * 4);
  int*   bsum   = (int*)alloc(1024);
  int*   flag   = (int*)alloc(256);
  int*   nbr    = (int*)alloc((size_t)Ee * 4);
  int*   col32  = (int*)alloc((size_t)Ee * 4);
  // row32 aliases [h | zsA]: dead before mlp_k writes h/zsA (mlp runs after scatter_x).
  int*   row32  = (int*)h;

  hipMemsetAsync(cnt, 0, (size_t)Nn * 4, stream);
  detect_k<<<1, 64, 0, stream>>>(ei, flag);
  cvt_k<<<(Ee + 255) / 256, 256, 0, stream>>>(ei, row32, col32, cnt, flag, Ee);
  dinv_k<<<(Nn + 255) / 256, 256, 0, stream>>>(cnt, dinv, Nn);
  int nb = (Nn + 1023) / 1024;
  scan_blocks<<<nb, 256, 0, stream>>>(cnt, offs, bsum, Nn);
  scan_top<<<1, 128, 0, stream>>>(bsum, nb);
  scan_add<<<nb, 256, 0, stream>>>(offs, bsum, cursor, Nn);
  int nph = (Nn + PHASE_DIV - 1) / PHASE_DIV;
  scatter_x<<<1024, 256, 0, stream>>>(row32, col32, cursor, nbr, Ee, nph);
  // mlp AFTER scatter so row32's alias region (h, zsA) is free during the scatter
  mlp_k<<<(Nn + 63) / 64, 256, 0, stream>>>(x, W1, b1, W2, b2, dinv, h, zsA, Nn);

  for (int it = 0; it < 10; ++it) {
    const float* zin = (it & 1) ? zsB : zsA;
    float* zout = (it & 1) ? zsA : zsB;
    int fin = (it == 9) ? 1 : 0;
    prop_k<<<(Nn + 15) / 16, 256, 0, stream>>>(zin, zout, h, offs, cnt, nbr,
                                               dinv, out, fin, Nn);
  }
}

// Round 9
// 1035.033 us; speedup vs baseline: 1.2852x; 1.0528x over previous
//
#include <hip/hip_runtime.h>
#include <hip/hip_bf16.h>

#define IN_F 512
#define HID_F 256
#define OUT_F 16
#define PHASE_DIV 12512   // dests per phase; 8 phases for N=100000; window ~1.6MB (< 4MB L2/XCD)
#define NXCD 8

typedef __bf16 bf8_t __attribute__((ext_vector_type(8)));
typedef float f4_t __attribute__((ext_vector_type(4)));
typedef unsigned short u16x4 __attribute__((ext_vector_type(4)));
typedef unsigned short u16x8 __attribute__((ext_vector_type(8)));

__device__ __forceinline__ unsigned short f2b(float f) {
  union { float f; unsigned u; } a; a.f = f;
  unsigned u = a.u;
  u += 0x7fffu + ((u >> 16) & 1u);   // round-to-nearest-even bf16
  return (unsigned short)(u >> 16);
}

// Detect whether edge_index arrived as int64 (odd 32-bit words all zero) or int32.
__global__ void detect_k(const int* __restrict__ ei, int* __restrict__ flag) {
  if (threadIdx.x == 0 && blockIdx.x == 0) {
    int is64 = 1;
    for (int i = 0; i < 16; ++i)
      if (ei[2 * i + 1] != 0) is64 = 0;
    *flag = is64;
  }
}

// One-time W1/W2 f32 -> bf16 conversion (W1b L2-resident thereafter).
__global__ void wcvt_k(const float* __restrict__ W1, const float* __restrict__ W2,
                       unsigned short* __restrict__ W1b, unsigned short* __restrict__ W2b) {
  int g = blockIdx.x * 256 + threadIdx.x;
  const int NW1 = (HID_F * IN_F) / 8;   // 16384 groups of 8
  const int NW2 = (OUT_F * HID_F) / 8;  // 512 groups
  if (g < NW1) {
    float4 v0 = ((const float4*)W1)[2 * g];
    float4 v1 = ((const float4*)W1)[2 * g + 1];
    u16x8 s = { f2b(v0.x), f2b(v0.y), f2b(v0.z), f2b(v0.w),
                f2b(v1.x), f2b(v1.y), f2b(v1.z), f2b(v1.w) };
    ((u16x8*)W1b)[g] = s;
  } else if (g < NW1 + NW2) {
    int q = g - NW1;
    float4 v0 = ((const float4*)W2)[2 * q];
    float4 v1 = ((const float4*)W2)[2 * q + 1];
    u16x8 s = { f2b(v0.x), f2b(v0.y), f2b(v0.z), f2b(v0.w),
                f2b(v1.x), f2b(v1.y), f2b(v1.z), f2b(v1.w) };
    ((u16x8*)W2b)[q] = s;
  }
}

// Convert edge list to packed int32 row/col arrays + fused in-degree histogram.
__global__ void cvt_k(const int* __restrict__ ei, int* __restrict__ row32,
                      int* __restrict__ col32, int* __restrict__ cnt,
                      const int* __restrict__ flag, int E_) {
  int e = blockIdx.x * 256 + threadIdx.x;
  if (e >= E_) return;
  int r, c;
  if (*flag) {
    const long long* e64 = (const long long*)ei;
    r = (int)e64[e];
    c = (int)e64[E_ + e];
  } else {
    r = ei[e];
    c = ei[E_ + e];
  }
  row32[e] = r;
  col32[e] = c;
  atomicAdd(&cnt[c], 1);
}

__global__ void dinv_k(const int* __restrict__ cnt, float* __restrict__ dinv, int n) {
  int i = blockIdx.x * 256 + threadIdx.x;
  if (i < n) dinv[i] = rsqrtf((float)(cnt[i] + 1));
}

// Fused MLP v2: h = relu(x@W1^T + b1) @ W2^T + b2; also writes zs0 = dinv*h.
// - W1/W2 pre-converted bf16 (wcvt_k); W1 fragments read DIRECT from global (L2).
// - GEMM1 mfma operands swapped: D rows = hid, cols = node -> epilogue is u16x4
//   vector LDS writes (was 64 scalar 2B stores at 4-way conflict).
// - K_STEP=64, a_sh row stride 72 (144B = 9 odd granules, balanced b128).
__global__ __launch_bounds__(256) void mlp_k(
    const float* __restrict__ x, const unsigned short* __restrict__ W1b,
    const float* __restrict__ b1, const unsigned short* __restrict__ W2b,
    const float* __restrict__ b2, const float* __restrict__ dinv,
    float* __restrict__ h, float* __restrict__ zs0, int n) {
  __shared__ unsigned short a_sh[64][72];     // 64 nodes x 64 k (pad->72)
  __shared__ unsigned short hid_sh[64][264];  // 64 nodes x 256 hid (pad 8)
  __shared__ unsigned short w2_sh[16][264];   // 16 out x 256 hid
  int tid = threadIdx.x;
  int node0 = blockIdx.x * 64;
  int wvid = tid >> 6;
  int lane = tid & 63;
  int row16 = lane & 15;
  int kg = lane >> 4;

  // stage W2b (16x256 bf16) -> LDS, plain copy
  {
    int r = tid >> 4;
    int c0 = (tid & 15) * 16;
    const u16x8* src = (const u16x8*)(W2b + r * HID_F + c0);
    *(u16x8*)&w2_sh[r][c0] = src[0];
    *(u16x8*)&w2_sh[r][c0 + 8] = src[1];
  }

  f4_t acc[4][4];
  #pragma unroll
  for (int mi = 0; mi < 4; ++mi)
    #pragma unroll
    for (int ni = 0; ni < 4; ++ni)
      acc[mi][ni] = (f4_t){0.f, 0.f, 0.f, 0.f};

  // per-wave W1b fragment base: rows wvid*64 + ni*16 + row16
  const unsigned short* wbase = W1b + (size_t)(wvid * 64 + row16) * IN_F + kg * 8;

  int arow = tid >> 2;            // staging: row 0..63
  int acol = (tid & 3) * 16;      // 16 k-elems per thread
  int anode = node0 + arow;
  const float* xrow = x + (size_t)anode * IN_F + acol;

  for (int kc = 0; kc < 8; ++kc) {
    int kb = kc * 64;
    __syncthreads();
    // stage A: x[64 nodes][kb..kb+63] -> bf16
    {
      float4 v0, v1, v2, v3;
      if (anode < n) {
        v0 = *(const float4*)(xrow + kb);
        v1 = *(const float4*)(xrow + kb + 4);
        v2 = *(const float4*)(xrow + kb + 8);
        v3 = *(const float4*)(xrow + kb + 12);
      } else {
        v0 = v1 = v2 = v3 = (float4){0.f, 0.f, 0.f, 0.f};
      }
      u16x8 s0 = { f2b(v0.x), f2b(v0.y), f2b(v0.z), f2b(v0.w),
                   f2b(v1.x), f2b(v1.y), f2b(v1.z), f2b(v1.w) };
      u16x8 s1 = { f2b(v2.x), f2b(v2.y), f2b(v2.z), f2b(v2.w),
                   f2b(v3.x), f2b(v3.y), f2b(v3.z), f2b(v3.w) };
      *(u16x8*)&a_sh[arow][acol] = s0;
      *(u16x8*)&a_sh[arow][acol + 8] = s1;
    }
    __syncthreads();
    #pragma unroll
    for (int ks = 0; ks < 2; ++ks) {
      bf8_t af[4], bfr[4];
      #pragma unroll
      for (int ni = 0; ni < 4; ++ni)
        bfr[ni] = *(const bf8_t*)(wbase + ni * 16 * IN_F + kb + ks * 32);
      #pragma unroll
      for (int mi = 0; mi < 4; ++mi)
        af[mi] = *(const bf8_t*)&a_sh[mi * 16 + row16][ks * 32 + kg * 8];
      #pragma unroll
      for (int mi = 0; mi < 4; ++mi)
        #pragma unroll
        for (int ni = 0; ni < 4; ++ni)
          acc[mi][ni] = __builtin_amdgcn_mfma_f32_16x16x32_bf16(bfr[ni], af[mi], acc[mi][ni], 0, 0, 0);
    }
  }
  __syncthreads();
  // epilogue 1: +b1, relu -> hid_sh bf16.
  // Swapped layout: lane holds node = mi*16+row16 (fixed), hid = wvid*64+ni*16+kg*4+r.
  #pragma unroll
  for (int ni = 0; ni < 4; ++ni) {
    int hb = wvid * 64 + ni * 16 + kg * 4;
    float4 bias4 = *(const float4*)&b1[hb];
    #pragma unroll
    for (int mi = 0; mi < 4; ++mi) {
      int nl = mi * 16 + row16;
      float v0 = fmaxf(acc[mi][ni][0] + bias4.x, 0.f);
      float v1 = fmaxf(acc[mi][ni][1] + bias4.y, 0.f);
      float v2 = fmaxf(acc[mi][ni][2] + bias4.z, 0.f);
      float v3 = fmaxf(acc[mi][ni][3] + bias4.w, 0.f);
      u16x4 s = { f2b(v0), f2b(v1), f2b(v2), f2b(v3) };
      *(u16x4*)&hid_sh[nl][hb] = s;
    }
  }
  __syncthreads();
  // GEMM2: each wave does 16 nodes x 16 out, K=256
  f4_t acc2 = (f4_t){0.f, 0.f, 0.f, 0.f};
  #pragma unroll
  for (int kc = 0; kc < 8; ++kc) {
    bf8_t a2  = *(const bf8_t*)&hid_sh[wvid * 16 + row16][kc * 32 + kg * 8];
    bf8_t b2f = *(const bf8_t*)&w2_sh[row16][kc * 32 + kg * 8];
    acc2 = __builtin_amdgcn_mfma_f32_16x16x32_bf16(a2, b2f, acc2, 0, 0, 0);
  }
  float bias2 = b2[row16];
  #pragma unroll
  for (int r = 0; r < 4; ++r) {
    int nl = wvid * 16 + kg * 4 + r;
    int node = node0 + nl;
    if (node < n) {
      float v = acc2[r] + bias2;
      h[(size_t)node * OUT_F + row16] = v;
      zs0[(size_t)node * OUT_F + row16] = dinv[node] * v;
    }
  }
}

// block-level exclusive scan (1024 elems/block, 4/thread)
__global__ void scan_blocks(const int* __restrict__ cnt, int* __restrict__ offs,
                            int* __restrict__ bsum, int n) {
  __shared__ int wsum[4];
  int tid = threadIdx.x;
  int base = blockIdx.x * 1024 + tid * 4;
  int v0 = (base + 0 < n) ? cnt[base + 0] : 0;
  int v1 = (base + 1 < n) ? cnt[base + 1] : 0;
  int v2 = (base + 2 < n) ? cnt[base + 2] : 0;
  int v3 = (base + 3 < n) ? cnt[base + 3] : 0;
  int tsum = v0 + v1 + v2 + v3;
  int lane = tid & 63, wv = tid >> 6;
  int inc = tsum;
  #pragma unroll
  for (int off = 1; off < 64; off <<= 1) {
    int t = __shfl_up(inc, off, 64);
    if (lane >= off) inc += t;
  }
  if (lane == 63) wsum[wv] = inc;
  __syncthreads();
  int add = 0;
  #pragma unroll
  for (int j = 0; j < 4; ++j)
    if (j < wv) add += wsum[j];
  int ex = add + inc - tsum;
  if (base + 0 < n) offs[base + 0] = ex;
  if (base + 1 < n) offs[base + 1] = ex + v0;
  if (base + 2 < n) offs[base + 2] = ex + v0 + v1;
  if (base + 3 < n) offs[base + 3] = ex + v0 + v1 + v2;
  if (tid == 255) bsum[blockIdx.x] = add + inc;
}

// exclusive scan of block sums (nb <= 128), one block of 128 threads
__global__ void scan_top(int* __restrict__ bsum, int nb) {
  __shared__ int w0;
  int tid = threadIdx.x;
  int v = (tid < nb) ? bsum[tid] : 0;
  int inc = v;
  #pragma unroll
  for (int off = 1; off < 64; off <<= 1) {
    int t = __shfl_up(inc, off, 64);
    if ((tid & 63) >= off) inc += t;
  }
  if (tid == 63) w0 = inc;
  __syncthreads();
  int ex = inc - v + ((tid >= 64) ? w0 : 0);
  if (tid < nb) bsum[tid] = ex;
}

__global__ void scan_add(int* __restrict__ offs, const int* __restrict__ bsum,
                         int* __restrict__ cursor, int n) {
  int base = blockIdx.x * 1024 + threadIdx.x * 4;
  int b = bsum[blockIdx.x];
  #pragma unroll
  for (int j = 0; j < 4; ++j) {
    int i = base + j;
    if (i < n) { int v = offs[i] + b; offs[i] = v; cursor[i] = v; }
  }
}

// XCD-pinned phased CSR scatter (see Round-7 notes).
__global__ __launch_bounds__(256) void scatter_x(
    const int* __restrict__ row32, const int* __restrict__ col32,
    int* __restrict__ cursor, int* __restrict__ nbr, int E_, int nph) {
  int grp = blockIdx.x & (NXCD - 1);
  int bid = blockIdx.x >> 3;                 // index within group
  int nbk = gridDim.x >> 3;                  // blocks per group
  int stride = nbk * 256;
  for (int p = grp; p < nph; p += NXCD) {
    for (int e = bid * 256 + threadIdx.x; e < E_; e += stride) {
      int c = col32[e];
      if (c / PHASE_DIV == p) {
        int pos = atomicAdd(&cursor[c], 1);
        nbr[pos] = row32[e];
      }
    }
  }
}

// one APPNP iteration on the pre-scaled iterate zs = dinv*z (see Round-6 notes).
__global__ __launch_bounds__(256) void prop_k(
    const float* __restrict__ zs_in, float* __restrict__ zs_out,
    const float* __restrict__ h, const int* __restrict__ offs,
    const int* __restrict__ cnt, const int* __restrict__ nbr,
    const float* __restrict__ dinv, float* __restrict__ out, int fin, int n) {
  int tid = threadIdx.x;
  int node = blockIdx.x * 16 + (tid >> 4);
  int lane = tid & 15;
  if (node >= n) return;
  float di = dinv[node];
  int base = node * OUT_F + lane;
  float a0 = zs_in[base];   // self loop term
  float a1 = 0.f;
  int s = offs[node];
  int end = s + cnt[node];
  int e = s;
  for (; e + 4 <= end; e += 4) {
    int j0 = nbr[e], j1 = nbr[e + 1], j2 = nbr[e + 2], j3 = nbr[e + 3];
    a0 += zs_in[j0 * OUT_F + lane];
    a1 += zs_in[j1 * OUT_F + lane];
    a0 += zs_in[j2 * OUT_F + lane];
    a1 += zs_in[j3 * OUT_F + lane];
  }
  for (; e < end; ++e) a0 += zs_in[nbr[e] * OUT_F + lane];
  float z = 0.9f * di * (a0 + a1) + 0.1f * h[base];
  if (!fin) {
    zs_out[base] = di * z;
  } else {
    float m = z;
    #pragma unroll
    for (int sdx = 8; sdx; sdx >>= 1) m = fmaxf(m, __shfl_xor(m, sdx, 16));
    float ex = expf(z - m);
    float t = ex;
    #pragma unroll
    for (int sdx = 8; sdx; sdx >>= 1) t += __shfl_xor(t, sdx, 16);
    out[base] = z - m - logf(t);
  }
}

extern "C" void kernel_launch(void* const* d_in, const int* in_sizes, int n_in,
                              void* d_out, int out_size, void* d_ws, size_t ws_size,
                              hipStream_t stream) {
  const int Nn = in_sizes[0] / IN_F;
  const int Ee = in_sizes[1] / 2;
  const float* x  = (const float*)d_in[0];
  const int*   ei = (const int*)d_in[1];
  const float* W1 = (const float*)d_in[2];
  const float* b1 = (const float*)d_in[3];
  const float* W2 = (const float*)d_in[4];
  const float* b2 = (const float*)d_in[5];
  float* out = (float*)d_out;

  char* w = (char*)d_ws;
  auto alloc = [&](size_t bytes) {
    char* p = w;
    w += (bytes + 255) & ~(size_t)255;
    return p;
  };
  float* h      = (float*)alloc((size_t)Nn * OUT_F * 4);
  float* zsA    = (float*)alloc((size_t)Nn * OUT_F * 4);
  float* zsB    = (float*)alloc((size_t)Nn * OUT_F * 4);
  int*   cnt    = (int*)alloc((size_t)Nn * 4);
  float* dinv   = (float*)alloc((size_t)Nn * 4);
  int*   offs   = (int*)alloc((size_t)Nn * 4);
  int*   cursor = (int*)alloc((size_t)Nn * 4);
  int*   bsum   = (int*)alloc(1024);
  int*   flag   = (int*)alloc(256);
  int*   nbr    = (int*)alloc((size_t)Ee * 4);
  int*   col32  = (int*)alloc((size_t)Ee * 4);
  unsigned short* W1b = (unsigned short*)alloc((size_t)HID_F * IN_F * 2);
  unsigned short* W2b = (unsigned short*)alloc((size_t)OUT_F * HID_F * 2);
  // row32 aliases [h | zsA]: dead before mlp_k writes h/zsA (mlp runs after scatter_x).
  int*   row32  = (int*)h;

  hipMemsetAsync(cnt, 0, (size_t)Nn * 4, stream);
  detect_k<<<1, 64, 0, stream>>>(ei, flag);
  wcvt_k<<<66, 256, 0, stream>>>(W1, W2, W1b, W2b);
  cvt_k<<<(Ee + 255) / 256, 256, 0, stream>>>(ei, row32, col32, cnt, flag, Ee);
  dinv_k<<<(Nn + 255) / 256, 256, 0, stream>>>(cnt, dinv, Nn);
  int nb = (Nn + 1023) / 1024;
  scan_blocks<<<nb, 256, 0, stream>>>(cnt, offs, bsum, Nn);
  scan_top<<<1, 128, 0, stream>>>(bsum, nb);
  scan_add<<<nb, 256, 0, stream>>>(offs, bsum, cursor, Nn);
  int nph = (Nn + PHASE_DIV - 1) / PHASE_DIV;
  scatter_x<<<1024, 256, 0, stream>>>(row32, col32, cursor, nbr, Ee, nph);
  // mlp AFTER scatter so row32's alias region (h, zsA) is free during the scatter
  mlp_k<<<(Nn + 63) / 64, 256, 0, stream>>>(x, W1b, b1, W2b, b2, dinv, h, zsA, Nn);

  for (int it = 0; it < 10; ++it) {
    const float* zin = (it & 1) ? zsB : zsA;
    float* zout = (it & 1) ? zsA : zsB;
    int fin = (it == 9) ? 1 : 0;
    prop_k<<<(Nn + 15) / 16, 256, 0, stream>>>(zin, zout, h, offs, cnt, nbr,
                                               dinv, out, fin, Nn);
  }
}

// Round 10
// 946.934 us; speedup vs baseline: 1.4047x; 1.0930x over previous
//
#include <hip/hip_runtime.h>
#include <hip/hip_bf16.h>

#define IN_F 512
#define HID_F 256
#define OUT_F 16
#define PHASE_DIV 12512   // dests per phase; 8 phases for N=100000; window ~1.6MB (< 4MB L2/XCD)
#define NXCD 8

typedef __bf16 bf8_t __attribute__((ext_vector_type(8)));
typedef float f4_t __attribute__((ext_vector_type(4)));
typedef unsigned short u16x4 __attribute__((ext_vector_type(4)));
typedef unsigned short u16x8 __attribute__((ext_vector_type(8)));

__device__ __forceinline__ unsigned short f2b(float f) {
  union { float f; unsigned u; } a; a.f = f;
  unsigned u = a.u;
  u += 0x7fffu + ((u >> 16) & 1u);   // round-to-nearest-even bf16
  return (unsigned short)(u >> 16);
}
__device__ __forceinline__ float b2f(unsigned short s) {
  union { unsigned u; float f; } a; a.u = ((unsigned)s) << 16; return a.f;
}

// Detect whether edge_index arrived as int64 (odd 32-bit words all zero) or int32.
__global__ void detect_k(const int* __restrict__ ei, int* __restrict__ flag) {
  if (threadIdx.x == 0 && blockIdx.x == 0) {
    int is64 = 1;
    for (int i = 0; i < 16; ++i)
      if (ei[2 * i + 1] != 0) is64 = 0;
    *flag = is64;
  }
}

// One-time W1/W2 f32 -> bf16 conversion (W1b L2-resident thereafter).
__global__ void wcvt_k(const float* __restrict__ W1, const float* __restrict__ W2,
                       unsigned short* __restrict__ W1b, unsigned short* __restrict__ W2b) {
  int g = blockIdx.x * 256 + threadIdx.x;
  const int NW1 = (HID_F * IN_F) / 8;   // 16384 groups of 8
  const int NW2 = (OUT_F * HID_F) / 8;  // 512 groups
  if (g < NW1) {
    float4 v0 = ((const float4*)W1)[2 * g];
    float4 v1 = ((const float4*)W1)[2 * g + 1];
    u16x8 s = { f2b(v0.x), f2b(v0.y), f2b(v0.z), f2b(v0.w),
                f2b(v1.x), f2b(v1.y), f2b(v1.z), f2b(v1.w) };
    ((u16x8*)W1b)[g] = s;
  } else if (g < NW1 + NW2) {
    int q = g - NW1;
    float4 v0 = ((const float4*)W2)[2 * q];
    float4 v1 = ((const float4*)W2)[2 * q + 1];
    u16x8 s = { f2b(v0.x), f2b(v0.y), f2b(v0.z), f2b(v0.w),
                f2b(v1.x), f2b(v1.y), f2b(v1.z), f2b(v1.w) };
    ((u16x8*)W2b)[q] = s;
  }
}

// Convert edge list to packed int32 row/col arrays + fused in-degree histogram.
__global__ void cvt_k(const int* __restrict__ ei, int* __restrict__ row32,
                      int* __restrict__ col32, int* __restrict__ cnt,
                      const int* __restrict__ flag, int E_) {
  int e = blockIdx.x * 256 + threadIdx.x;
  if (e >= E_) return;
  int r, c;
  if (*flag) {
    const long long* e64 = (const long long*)ei;
    r = (int)e64[e];
    c = (int)e64[E_ + e];
  } else {
    r = ei[e];
    c = ei[E_ + e];
  }
  row32[e] = r;
  col32[e] = c;
  atomicAdd(&cnt[c], 1);
}

__global__ void dinv_k(const int* __restrict__ cnt, float* __restrict__ dinv, int n) {
  int i = blockIdx.x * 256 + threadIdx.x;
  if (i < n) dinv[i] = rsqrtf((float)(cnt[i] + 1));
}

// Fused MLP v2: h = relu(x@W1^T + b1) @ W2^T + b2; writes h (f32) and zs0 = bf16(dinv*h).
__global__ __launch_bounds__(256) void mlp_k(
    const float* __restrict__ x, const unsigned short* __restrict__ W1b,
    const float* __restrict__ b1, const unsigned short* __restrict__ W2b,
    const float* __restrict__ b2, const float* __restrict__ dinv,
    float* __restrict__ h, unsigned short* __restrict__ zs0, int n) {
  __shared__ unsigned short a_sh[64][72];     // 64 nodes x 64 k (pad->72)
  __shared__ unsigned short hid_sh[64][264];  // 64 nodes x 256 hid (pad 8)
  __shared__ unsigned short w2_sh[16][264];   // 16 out x 256 hid
  int tid = threadIdx.x;
  int node0 = blockIdx.x * 64;
  int wvid = tid >> 6;
  int lane = tid & 63;
  int row16 = lane & 15;
  int kg = lane >> 4;

  // stage W2b (16x256 bf16) -> LDS, plain copy
  {
    int r = tid >> 4;
    int c0 = (tid & 15) * 16;
    const u16x8* src = (const u16x8*)(W2b + r * HID_F + c0);
    *(u16x8*)&w2_sh[r][c0] = src[0];
    *(u16x8*)&w2_sh[r][c0 + 8] = src[1];
  }

  f4_t acc[4][4];
  #pragma unroll
  for (int mi = 0; mi < 4; ++mi)
    #pragma unroll
    for (int ni = 0; ni < 4; ++ni)
      acc[mi][ni] = (f4_t){0.f, 0.f, 0.f, 0.f};

  // per-wave W1b fragment base: rows wvid*64 + ni*16 + row16
  const unsigned short* wbase = W1b + (size_t)(wvid * 64 + row16) * IN_F + kg * 8;

  int arow = tid >> 2;            // staging: row 0..63
  int acol = (tid & 3) * 16;      // 16 k-elems per thread
  int anode = node0 + arow;
  const float* xrow = x + (size_t)anode * IN_F + acol;

  for (int kc = 0; kc < 8; ++kc) {
    int kb = kc * 64;
    __syncthreads();
    // stage A: x[64 nodes][kb..kb+63] -> bf16
    {
      float4 v0, v1, v2, v3;
      if (anode < n) {
        v0 = *(const float4*)(xrow + kb);
        v1 = *(const float4*)(xrow + kb + 4);
        v2 = *(const float4*)(xrow + kb + 8);
        v3 = *(const float4*)(xrow + kb + 12);
      } else {
        v0 = v1 = v2 = v3 = (float4){0.f, 0.f, 0.f, 0.f};
      }
      u16x8 s0 = { f2b(v0.x), f2b(v0.y), f2b(v0.z), f2b(v0.w),
                   f2b(v1.x), f2b(v1.y), f2b(v1.z), f2b(v1.w) };
      u16x8 s1 = { f2b(v2.x), f2b(v2.y), f2b(v2.z), f2b(v2.w),
                   f2b(v3.x), f2b(v3.y), f2b(v3.z), f2b(v3.w) };
      *(u16x8*)&a_sh[arow][acol] = s0;
      *(u16x8*)&a_sh[arow][acol + 8] = s1;
    }
    __syncthreads();
    #pragma unroll
    for (int ks = 0; ks < 2; ++ks) {
      bf8_t af[4], bfr[4];
      #pragma unroll
      for (int ni = 0; ni < 4; ++ni)
        bfr[ni] = *(const bf8_t*)(wbase + ni * 16 * IN_F + kb + ks * 32);
      #pragma unroll
      for (int mi = 0; mi < 4; ++mi)
        af[mi] = *(const bf8_t*)&a_sh[mi * 16 + row16][ks * 32 + kg * 8];
      #pragma unroll
      for (int mi = 0; mi < 4; ++mi)
        #pragma unroll
        for (int ni = 0; ni < 4; ++ni)
          acc[mi][ni] = __builtin_amdgcn_mfma_f32_16x16x32_bf16(bfr[ni], af[mi], acc[mi][ni], 0, 0, 0);
    }
  }
  __syncthreads();
  // epilogue 1: +b1, relu -> hid_sh bf16 (vector u16x4 stores; swapped C layout).
  #pragma unroll
  for (int ni = 0; ni < 4; ++ni) {
    int hb = wvid * 64 + ni * 16 + kg * 4;
    float4 bias4 = *(const float4*)&b1[hb];
    #pragma unroll
    for (int mi = 0; mi < 4; ++mi) {
      int nl = mi * 16 + row16;
      float v0 = fmaxf(acc[mi][ni][0] + bias4.x, 0.f);
      float v1 = fmaxf(acc[mi][ni][1] + bias4.y, 0.f);
      float v2 = fmaxf(acc[mi][ni][2] + bias4.z, 0.f);
      float v3 = fmaxf(acc[mi][ni][3] + bias4.w, 0.f);
      u16x4 s = { f2b(v0), f2b(v1), f2b(v2), f2b(v3) };
      *(u16x4*)&hid_sh[nl][hb] = s;
    }
  }
  __syncthreads();
  // GEMM2: each wave does 16 nodes x 16 out, K=256
  f4_t acc2 = (f4_t){0.f, 0.f, 0.f, 0.f};
  #pragma unroll
  for (int kc = 0; kc < 8; ++kc) {
    bf8_t a2  = *(const bf8_t*)&hid_sh[wvid * 16 + row16][kc * 32 + kg * 8];
    bf8_t b2f = *(const bf8_t*)&w2_sh[row16][kc * 32 + kg * 8];
    acc2 = __builtin_amdgcn_mfma_f32_16x16x32_bf16(a2, b2f, acc2, 0, 0, 0);
  }
  float bias2 = b2[row16];
  #pragma unroll
  for (int r = 0; r < 4; ++r) {
    int nl = wvid * 16 + kg * 4 + r;
    int node = node0 + nl;
    if (node < n) {
      float v = acc2[r] + bias2;
      h[(size_t)node * OUT_F + row16] = v;
      zs0[(size_t)node * OUT_F + row16] = f2b(dinv[node] * v);
    }
  }
}

// block-level exclusive scan (1024 elems/block, 4/thread)
__global__ void scan_blocks(const int* __restrict__ cnt, int* __restrict__ offs,
                            int* __restrict__ bsum, int n) {
  __shared__ int wsum[4];
  int tid = threadIdx.x;
  int base = blockIdx.x * 1024 + tid * 4;
  int v0 = (base + 0 < n) ? cnt[base + 0] : 0;
  int v1 = (base + 1 < n) ? cnt[base + 1] : 0;
  int v2 = (base + 2 < n) ? cnt[base + 2] : 0;
  int v3 = (base + 3 < n) ? cnt[base + 3] : 0;
  int tsum = v0 + v1 + v2 + v3;
  int lane = tid & 63, wv = tid >> 6;
  int inc = tsum;
  #pragma unroll
  for (int off = 1; off < 64; off <<= 1) {
    int t = __shfl_up(inc, off, 64);
    if (lane >= off) inc += t;
  }
  if (lane == 63) wsum[wv] = inc;
  __syncthreads();
  int add = 0;
  #pragma unroll
  for (int j = 0; j < 4; ++j)
    if (j < wv) add += wsum[j];
  int ex = add + inc - tsum;
  if (base + 0 < n) offs[base + 0] = ex;
  if (base + 1 < n) offs[base + 1] = ex + v0;
  if (base + 2 < n) offs[base + 2] = ex + v0 + v1;
  if (base + 3 < n) offs[base + 3] = ex + v0 + v1 + v2;
  if (tid == 255) bsum[blockIdx.x] = add + inc;
}

// exclusive scan of block sums (nb <= 128), one block of 128 threads
__global__ void scan_top(int* __restrict__ bsum, int nb) {
  __shared__ int w0;
  int tid = threadIdx.x;
  int v = (tid < nb) ? bsum[tid] : 0;
  int inc = v;
  #pragma unroll
  for (int off = 1; off < 64; off <<= 1) {
    int t = __shfl_up(inc, off, 64);
    if ((tid & 63) >= off) inc += t;
  }
  if (tid == 63) w0 = inc;
  __syncthreads();
  int ex = inc - v + ((tid >= 64) ? w0 : 0);
  if (tid < nb) bsum[tid] = ex;
}

__global__ void scan_add(int* __restrict__ offs, const int* __restrict__ bsum,
                         int* __restrict__ cursor, int n) {
  int base = blockIdx.x * 1024 + threadIdx.x * 4;
  int b = bsum[blockIdx.x];
  #pragma unroll
  for (int j = 0; j < 4; ++j) {
    int i = base + j;
    if (i < n) { int v = offs[i] + b; offs[i] = v; cursor[i] = v; }
  }
}

// XCD-pinned phased CSR scatter. NEW: edge-stream loads are NON-TEMPORAL so
// the 25.6MB/phase read stream doesn't evict the ~1.6MB L2-resident nbr
// write window (Round-9 lesson: stream-vs-window L2 contention, not window
// size, kept WRITE_SIZE at 174MB).
__global__ __launch_bounds__(256) void scatter_x(
    const int* __restrict__ row32, const int* __restrict__ col32,
    int* __restrict__ cursor, int* __restrict__ nbr, int E_, int nph) {
  int grp = blockIdx.x & (NXCD - 1);
  int bid = blockIdx.x >> 3;                 // index within group
  int nbk = gridDim.x >> 3;                  // blocks per group
  int stride = nbk * 256;
  for (int p = grp; p < nph; p += NXCD) {
    for (int e = bid * 256 + threadIdx.x; e < E_; e += stride) {
      int c = __builtin_nontemporal_load(&col32[e]);
      if (c / PHASE_DIV == p) {
        int r = __builtin_nontemporal_load(&row32[e]);
        int pos = atomicAdd(&cursor[c], 1);
        nbr[pos] = r;
      }
    }
  }
}

// one APPNP iteration on the bf16 pre-scaled iterate zs = bf16(dinv*z):
//   z_new[i]  = 0.9 * dinv[i] * (zs_self + sum_{j in in(i)} zs[j]) + 0.1*h[i]
//   zs_out[i] = bf16(dinv[i] * z_new[i])
// zs is 3.2MB -> fits per-XCD L2; gathers mostly L2-hit, 2 nodes per 64B line.
__global__ __launch_bounds__(256) void prop_k(
    const unsigned short* __restrict__ zs_in, unsigned short* __restrict__ zs_out,
    const float* __restrict__ h, const int* __restrict__ offs,
    const int* __restrict__ cnt, const int* __restrict__ nbr,
    const float* __restrict__ dinv, float* __restrict__ out, int fin, int n) {
  int tid = threadIdx.x;
  int node = blockIdx.x * 16 + (tid >> 4);
  int lane = tid & 15;
  if (node >= n) return;
  float di = dinv[node];
  int base = node * OUT_F + lane;
  float a0 = b2f(zs_in[base]);   // self loop term
  float a1 = 0.f, a2 = 0.f, a3 = 0.f;
  int s = offs[node];
  int end = s + cnt[node];
  int e = s;
  for (; e + 8 <= end; e += 8) {
    int j0 = nbr[e], j1 = nbr[e + 1], j2 = nbr[e + 2], j3 = nbr[e + 3];
    int j4 = nbr[e + 4], j5 = nbr[e + 5], j6 = nbr[e + 6], j7 = nbr[e + 7];
    a0 += b2f(zs_in[j0 * OUT_F + lane]);
    a1 += b2f(zs_in[j1 * OUT_F + lane]);
    a2 += b2f(zs_in[j2 * OUT_F + lane]);
    a3 += b2f(zs_in[j3 * OUT_F + lane]);
    a0 += b2f(zs_in[j4 * OUT_F + lane]);
    a1 += b2f(zs_in[j5 * OUT_F + lane]);
    a2 += b2f(zs_in[j6 * OUT_F + lane]);
    a3 += b2f(zs_in[j7 * OUT_F + lane]);
  }
  for (; e < end; ++e) a0 += b2f(zs_in[nbr[e] * OUT_F + lane]);
  float z = 0.9f * di * ((a0 + a1) + (a2 + a3)) + 0.1f * h[base];
  if (!fin) {
    zs_out[base] = f2b(di * z);
  } else {
    float m = z;
    #pragma unroll
    for (int sdx = 8; sdx; sdx >>= 1) m = fmaxf(m, __shfl_xor(m, sdx, 16));
    float ex = expf(z - m);
    float t = ex;
    #pragma unroll
    for (int sdx = 8; sdx; sdx >>= 1) t += __shfl_xor(t, sdx, 16);
    out[base] = z - m - logf(t);
  }
}

extern "C" void kernel_launch(void* const* d_in, const int* in_sizes, int n_in,
                              void* d_out, int out_size, void* d_ws, size_t ws_size,
                              hipStream_t stream) {
  const int Nn = in_sizes[0] / IN_F;
  const int Ee = in_sizes[1] / 2;
  const float* x  = (const float*)d_in[0];
  const int*   ei = (const int*)d_in[1];
  const float* W1 = (const float*)d_in[2];
  const float* b1 = (const float*)d_in[3];
  const float* W2 = (const float*)d_in[4];
  const float* b2 = (const float*)d_in[5];
  float* out = (float*)d_out;

  char* w = (char*)d_ws;
  auto alloc = [&](size_t bytes) {
    char* p = w;
    w += (bytes + 255) & ~(size_t)255;
    return p;
  };
  float*          h   = (float*)alloc((size_t)Nn * OUT_F * 4);
  unsigned short* zsA = (unsigned short*)alloc((size_t)Nn * OUT_F * 2);
  unsigned short* zsB = (unsigned short*)alloc((size_t)Nn * OUT_F * 2);
  int*   cnt    = (int*)alloc((size_t)Nn * 4);
  float* dinv   = (float*)alloc((size_t)Nn * 4);
  int*   offs   = (int*)alloc((size_t)Nn * 4);
  int*   cursor = (int*)alloc((size_t)Nn * 4);
  int*   bsum   = (int*)alloc(1024);
  int*   flag   = (int*)alloc(256);
  int*   nbr    = (int*)alloc((size_t)Ee * 4);
  int*   col32  = (int*)alloc((size_t)Ee * 4);
  unsigned short* W1b = (unsigned short*)alloc((size_t)HID_F * IN_F * 2);
  unsigned short* W2b = (unsigned short*)alloc((size_t)OUT_F * HID_F * 2);
  // row32 aliases [h | zsA | zsB] (= 6.4+3.2+3.2 = 12.8MB = Ee*4): that whole
  // region is dead until after scatter_x (mlp writes h/zsA after; prop writes
  // zsB at it=0 after).
  int*   row32  = (int*)h;

  hipMemsetAsync(cnt, 0, (size_t)Nn * 4, stream);
  detect_k<<<1, 64, 0, stream>>>(ei, flag);
  wcvt_k<<<66, 256, 0, stream>>>(W1, W2, W1b, W2b);
  cvt_k<<<(Ee + 255) / 256, 256, 0, stream>>>(ei, row32, col32, cnt, flag, Ee);
  dinv_k<<<(Nn + 255) / 256, 256, 0, stream>>>(cnt, dinv, Nn);
  int nb = (Nn + 1023) / 1024;
  scan_blocks<<<nb, 256, 0, stream>>>(cnt, offs, bsum, Nn);
  scan_top<<<1, 128, 0, stream>>>(bsum, nb);
  scan_add<<<nb, 256, 0, stream>>>(offs, bsum, cursor, Nn);
  int nph = (Nn + PHASE_DIV - 1) / PHASE_DIV;
  scatter_x<<<1024, 256, 0, stream>>>(row32, col32, cursor, nbr, Ee, nph);
  // mlp AFTER scatter so row32's alias region (h, zsA, zsB) is free during the scatter
  mlp_k<<<(Nn + 63) / 64, 256, 0, stream>>>(x, W1b, b1, W2b, b2, dinv, h, zsA, Nn);

  for (int it = 0; it < 10; ++it) {
    const unsigned short* zin = (it & 1) ? zsB : zsA;
    unsigned short* zout = (it & 1) ? zsA : zsB;
    int fin = (it == 9) ? 1 : 0;
    prop_k<<<(Nn + 15) / 16, 256, 0, stream>>>(zin, zout, h, offs, cnt, nbr,
                                               dinv, out, fin, Nn);
  }
}